// Round 6
// baseline (17772.765 us; speedup 1.0000x reference)
//
#include <hip/hip_runtime.h>
#include <math.h>

#define HH 7
#define WW 18
#define PP 126        // HH*WW
#define CC 16
#define NN 4096
#define EE 16384
#define BB 64
#define TILE 2016               // CC*PP
#define RPAD 20                 // padded row length
#define NPAD (CC * HH * RPAD)   // 2240 floats per node tile (padded)
#define ZROWS 172               // MFMA probe LDS tile rows
#define STG 132
#define SPIN_UNIT 150000

typedef __attribute__((ext_vector_type(8))) short short8;
typedef __attribute__((ext_vector_type(4))) float f32x4;

__device__ __forceinline__ float sp_f(float x) {
    // softplus, JAX-stable form: max(x,0)+log1p(exp(-|x|))
    return fmaxf(x, 0.f) + log1pf(expf(-fabsf(x)));
}
__device__ __forceinline__ unsigned short f2bf(float f) {
    unsigned int u = __builtin_bit_cast(unsigned int, f);
    unsigned int r = u + 0x7fffu + ((u >> 16) & 1u);   // RNE
    return (unsigned short)(r >> 16);
}
__device__ __forceinline__ float bf2f(unsigned short h) {
    unsigned int u = ((unsigned int)h) << 16;
    return __builtin_bit_cast(float, u);
}
__device__ __forceinline__ void spin_k(int kiter) {
    if (kiter <= 0) return;
    float acc = (float)threadIdx.x;
    for (int i = 0; i < kiter; i++) acc = fmaf(acc, 1.0000001f, 0.125f);
    asm volatile("" :: "v"(acc));
}

// ---------------- weight transposes -> [tap][ci][co16][2] -------------------
__global__ void k_wT(const float* __restrict__ w, float* __restrict__ wT) {
    int i = blockIdx.x * 256 + threadIdx.x;
    if (i < 32 * 144) {
        int co = i / 144, r = i - co * 144, ci = r / 9, tap = r - ci * 9;
        int half = co >> 4, coo = co & 15;
        wT[((tap * 16 + ci) * 16 + coo) * 2 + half] = w[i];
    }
}
__global__ void k_wT2(const float* __restrict__ wN, const float* __restrict__ wE,
                      float* __restrict__ wT) {
    int i = blockIdx.x * 256 + threadIdx.x;
    if (i < 16 * 144) {
        int co = i / 144, r = i - co * 144, ci = r / 9, tap = r - ci * 9;
        wT[((tap * 16 + ci) * 16 + co) * 2 + 0] = wN[i];
        wT[((tap * 16 + ci) * 16 + co) * 2 + 1] = wE[i];
    }
}

// ---------------- embedding -------------------------------------------------
__global__ __launch_bounds__(256) void k_embed(const float* __restrict__ nodes,
                                               const float* __restrict__ w,
                                               const float* __restrict__ b,
                                               float* __restrict__ atom) {
    __shared__ float tile[PP];
    __shared__ float ws[CC * 9];
    __shared__ float bs[CC];
    int n = blockIdx.x, tid = threadIdx.x;
    for (int i = tid; i < PP; i += 256) tile[i] = nodes[n * PP + i];
    for (int i = tid; i < CC * 9; i += 256) ws[i] = w[i];
    if (tid < CC) bs[tid] = b[tid];
    __syncthreads();
    for (int i = tid; i < CC * PP; i += 256) {
        int c = i / PP, p = i - c * PP, y = p / WW, x = p - (p / WW) * WW;
        float acc = bs[c];
#pragma unroll
        for (int dy = 0; dy < 3; dy++) {
            int yy = y + dy - 1; if ((unsigned)yy >= (unsigned)HH) continue;
#pragma unroll
            for (int dx = 0; dx < 3; dx++) {
                int xx = x + dx - 1; if ((unsigned)xx >= (unsigned)WW) continue;
                acc += tile[yy * WW + xx] * ws[c * 9 + dy * 3 + dx];
            }
        }
        atom[(size_t)n * CC * PP + i] = sp_f(acc);
    }
}

// core conv macro body (R3, proven): accumulate (hA,hB) over ci,dy
#define CONV_BODY(ZT, HA, HB)                                                   \
    for (int ci = 0; ci < 16; ci++) {                                           \
        const float* zb = (ZT) + ci * (HH * RPAD);                              \
        _Pragma("unroll")                                                       \
        for (int dy = 0; dy < 3; dy++) {                                        \
            int yy = y + dy - 1;                                                \
            if ((unsigned)yy < (unsigned)HH) {                                  \
                const float* zr = zb + yy * RPAD;                               \
                float4 q0 = *(const float4*)&zr[0];                             \
                float4 q1 = *(const float4*)&zr[4];                             \
                float4 q2 = *(const float4*)&zr[8];                             \
                float4 q3 = *(const float4*)&zr[12];                            \
                float2 q4 = *(const float2*)&zr[16];                            \
                float r[18] = {q0.x, q0.y, q0.z, q0.w, q1.x, q1.y, q1.z, q1.w,  \
                               q2.x, q2.y, q2.z, q2.w, q3.x, q3.y, q3.z, q3.w,  \
                               q4.x, q4.y};                                     \
                float2 w0 = *(const float2*)&ws[dy * 3 + 0][ci][co][0];         \
                float2 w1 = *(const float2*)&ws[dy * 3 + 1][ci][co][0];         \
                float2 w2 = *(const float2*)&ws[dy * 3 + 2][ci][co][0];         \
                _Pragma("unroll")                                               \
                for (int x = 0; x < 18; x++) {                                  \
                    float a0 = r[x] * w1.x, a1 = r[x] * w1.y;                   \
                    if (x > 0)  { a0 += r[x - 1] * w0.x; a1 += r[x - 1] * w0.y; }\
                    if (x < 17) { a0 += r[x + 1] * w2.x; a1 += r[x + 1] * w2.y; }\
                    HA[x] += a0; HB[x] += a1;                                   \
                }                                                               \
            }                                                                   \
        }                                                                       \
    }

// ------------- per-node dual conv 16->16, 2 nodes/block (R3) ----------------
__global__ __launch_bounds__(256) void k_node_conv2(const float* __restrict__ atom,
                                                    const float* __restrict__ wT,
                                                    float* __restrict__ An,
                                                    float* __restrict__ Ae) {
    __shared__ __align__(16) float z[2 * NPAD];
    __shared__ __align__(16) float ws[9][16][16][2];
    int tid = threadIdx.x;
    int n0 = blockIdx.x * 2;
    for (int i = tid; i < 2 * NPAD; i += 256) {
        int e2 = i / NPAD, r = i - e2 * NPAD;
        int ci = r / (HH * RPAD), rr = r - ci * (HH * RPAD);
        int y = rr / RPAD, x = rr - y * RPAD;
        float v = 0.f;
        if (x < WW) v = atom[(size_t)(n0 + e2) * CC * PP + ci * PP + y * WW + x];
        z[i] = v;
    }
    for (int i = tid; i < 4608; i += 256) ((float*)ws)[i] = wT[i];
    __syncthreads();
    int grp = tid >> 7, lt = tid & 127;
    float hN[18], hE[18];
    bool act = lt < 112;
    int co = lt & 15, y = lt >> 4;
    if (act) {
#pragma unroll
        for (int x = 0; x < 18; x++) { hN[x] = 0.f; hE[x] = 0.f; }
        const float* zt = &z[grp * NPAD];
        CONV_BODY(zt, hN, hE)
    }
    __syncthreads();
    float* sN = z;
    float* sE = (float*)ws;
    if (act) {
        int base = grp * NPAD + co * (HH * RPAD) + y * RPAD;
#pragma unroll
        for (int x = 0; x < 18; x++) { sN[base + x] = hN[x]; sE[base + x] = hE[x]; }
        sN[base + 18] = 0.f; sN[base + 19] = 0.f;
        sE[base + 18] = 0.f; sE[base + 19] = 0.f;
    }
    __syncthreads();
    const float4* sN4 = (const float4*)sN;
    const float4* sE4 = (const float4*)sE;
    for (int i = tid; i < 2 * (NPAD / 4); i += 256) {
        int e2 = i / (NPAD / 4), j = i - e2 * (NPAD / 4);
        ((float4*)&An[(size_t)(n0 + e2) * NPAD])[j] = sN4[i];
        ((float4*)&Ae[(size_t)(n0 + e2) * NPAD])[j] = sE4[i];
    }
}

// ---------------- per-edge, 2 edges/block (R3, proven 500us) ----------------
__global__ __launch_bounds__(256) void k_edge(const float* __restrict__ An,
                                              const float* __restrict__ Ae,
                                              const int* __restrict__ es,
                                              const int* __restrict__ et,
                                              const float* __restrict__ lwT,
                                              const float* __restrict__ lb,
                                              float* __restrict__ outb) {
    __shared__ __align__(16) float z[2 * NPAD];
    __shared__ __align__(16) float ws[9][16][16][2];
    int tid = threadIdx.x;
    int e0 = blockIdx.x * 2;
    int s0 = es[e0], t0 = et[e0], s1 = es[e0 + 1], t1 = et[e0 + 1];
    for (int i = tid; i < 2 * (NPAD / 4); i += 256) {
        int e2 = i / (NPAD / 4), j = i - e2 * (NPAD / 4);
        int s = e2 ? s1 : s0, t = e2 ? t1 : t0;
        float4 av = ((const float4*)&An[(size_t)s * NPAD])[j];
        float4 ev = ((const float4*)&Ae[(size_t)t * NPAD])[j];
        float4 res;
        res.x = av.x * ev.x; res.x = res.x > 0.f ? res.x : expm1f(res.x);
        res.y = av.y * ev.y; res.y = res.y > 0.f ? res.y : expm1f(res.y);
        res.z = av.z * ev.z; res.z = res.z > 0.f ? res.z : expm1f(res.z);
        res.w = av.w * ev.w; res.w = res.w > 0.f ? res.w : expm1f(res.w);
        ((float4*)z)[i] = res;
    }
    for (int i = tid; i < 4608; i += 256) ((float*)ws)[i] = lwT[i];
    __syncthreads();
    int grp = tid >> 7, lt = tid & 127;
    bool act = lt < 112;
    int co = lt & 15, y = lt >> 4;
    float msg[18];
    if (act) {
        float hf[18], hc[18];
#pragma unroll
        for (int x = 0; x < 18; x++) { hf[x] = 0.f; hc[x] = 0.f; }
        const float* zt = &z[grp * NPAD];
        CONV_BODY(zt, hf, hc)
        float bf = lb[co], bc = lb[co + 16];
#pragma unroll
        for (int x = 0; x < 18; x++) {
            float hfv = hf[x] + bf, hcv = hc[x] + bc;
            float sig = 1.f / (1.f + expf(-hfv));
            msg[x] = sig * sp_f(hcv);
        }
    }
    __syncthreads();
    float* msgL = z;
    if (act) {
        int base = grp * (CC * PP) + co * PP + y * WW;
#pragma unroll
        for (int x = 0; x < 18; x++) msgL[base + x] = msg[x];
    }
    __syncthreads();
    for (int i = tid; i < 2 * CC * PP; i += 256) {
        int e2 = i / (CC * PP), j = i - e2 * (CC * PP);
        int s = e2 ? s1 : s0;
        unsafeAtomicAdd(&outb[(size_t)s * CC * PP + j], msgL[i]);
    }
}

// ==================== MFMA probe suite =====================================
// wprep: per-lane A fragments, bf16 hi/lo; fake_k(g,j) = (ci=(g&1)*8+j, tap=ks*2+(g>>1))
__global__ void k_wprep_edge(const float* __restrict__ lw,
                             short* __restrict__ fH, short* __restrict__ fL) {
    int idx = blockIdx.x * 256 + threadIdx.x;
    if (idx >= 5120) return;
    int j = idx & 7, lane = (idx >> 3) & 63, cotile = (idx >> 9) & 1, ks = idx >> 10;
    int co = cotile * 16 + (lane & 15);
    int ci = ((lane >> 4) & 1) * 8 + j;
    int tap = ks * 2 + (lane >> 5);
    float v = (tap > 8) ? 0.f : lw[(co * 16 + ci) * 9 + tap];
    unsigned short hi = f2bf(v);
    unsigned short lo = f2bf(v - bf2f(hi));
    fH[idx] = (short)hi; fL[idx] = (short)lo;
}

// probe1: A=B=1 -> every acc element must be exactly 32.0
__global__ void k_probe1(float* __restrict__ P) {
    int lane = threadIdx.x;
    short8 a, b;
#pragma unroll
    for (int j = 0; j < 8; j++) { a[j] = (short)0x3f80; b[j] = (short)0x3f80; }
    f32x4 c = {0.f, 0.f, 0.f, 0.f};
    c = __builtin_amdgcn_mfma_f32_16x16x32_bf16(a, b, c, 0, 0, 0);
#pragma unroll
    for (int r = 0; r < 4; r++) P[lane * 4 + r] = c[r];
}

// probe2: A=delta at (g=0,j=0); B[g][j]=g*8+j -> acc must be 0 everywhere;
// a constant integer v reveals B's partner position for A's k-slot 0.
__global__ void k_probe2(float* __restrict__ P) {
    int lane = threadIdx.x;
    short8 a, b;
#pragma unroll
    for (int j = 0; j < 8; j++) {
        a[j] = (lane < 16 && j == 0) ? (short)0x3f80 : (short)0;
        b[j] = (short)f2bf((float)((lane >> 4) * 8 + j));
    }
    f32x4 c = {0.f, 0.f, 0.f, 0.f};
    c = __builtin_amdgcn_mfma_f32_16x16x32_bf16(a, b, c, 0, 0, 0);
#pragma unroll
    for (int r = 0; r < 4; r++) P[lane * 4 + r] = c[r];
}

__global__ void k_check1(const float* __restrict__ P, int* __restrict__ dc) {
    __shared__ int red[256];
    int i = threadIdx.x;
    float d = fabsf(P[i] - 32.0f);
    int code = (d != d) ? 4 : (d > 0.5f ? 2 : 0);
    red[i] = code;
    __syncthreads();
    for (int off = 128; off > 0; off >>= 1) {
        if (i < off) red[i] = max(red[i], red[i + off]);
        __syncthreads();
    }
    if (i == 0) atomicMax(dc, red[0]);
}
__global__ void k_check2(const float* __restrict__ P, int* __restrict__ dc) {
    __shared__ int red[256];
    int i = threadIdx.x;
    float v = P[i];
    int code;
    if (v != v) code = 16;
    else {
        float rv = rintf(v);
        int iv = (int)rv;
        if (fabsf(v - rv) > 0.25f || iv < 0 || iv > 31) code = 16;
        else code = (iv == 0) ? 0 : 2 + (iv > 12 ? 12 : iv);
    }
    red[i] = code;
    __syncthreads();
    for (int off = 128; off > 0; off >>= 1) {
        if (i < off) red[i] = max(red[i], red[i + off]);
        __syncthreads();
    }
    if (i == 0) atomicMax(dc, red[0]);
}

// probe3/4: full R4 edge-MFMA on 4 edges (padded An/Ae input), dumping raw
// accumulator (Hdump) and final msg (Mdump).
#define MFMA_CORE(ACC)                                                          \
    int boff[5];                                                                \
    _Pragma("unroll")                                                           \
    for (int ks = 0; ks < 5; ks++) {                                            \
        int tap = ks * 2 + th; if (tap > 8) tap = 8;                            \
        boff[ks] = (tap / 3 - 1) * 19 + (tap - (tap / 3) * 3) - 1;              \
    }                                                                           \
    _Pragma("unroll")                                                           \
    for (int pt = 0; pt < 4; pt++) ACC[pt] = (f32x4){0.f, 0.f, 0.f, 0.f};       \
    _Pragma("unroll")                                                           \
    for (int pt = 0; pt < 4; pt++) {                                            \
        int p = (ph * 4 + pt) * 16 + colp;                                      \
        int y = 0, x = 0;                                                       \
        if (p < 126) { y = p / 18; x = p - y * 18; }                            \
        int bbase = (20 + y * 19 + x) * 16 + ciq * 8;                           \
        _Pragma("unroll")                                                       \
        for (int ks = 0; ks < 5; ks++) {                                        \
            short8 bh = *(const short8*)&zTh[bbase + boff[ks] * 16];            \
            short8 bl = *(const short8*)&zTl[bbase + boff[ks] * 16];            \
            ACC[pt] = __builtin_amdgcn_mfma_f32_16x16x32_bf16(wah[ks], bh, ACC[pt], 0, 0, 0); \
            ACC[pt] = __builtin_amdgcn_mfma_f32_16x16x32_bf16(wah[ks], bl, ACC[pt], 0, 0, 0); \
            ACC[pt] = __builtin_amdgcn_mfma_f32_16x16x32_bf16(wal[ks], bh, ACC[pt], 0, 0, 0); \
        }                                                                       \
    }

__global__ __launch_bounds__(256) void k_mfma4(const float* __restrict__ An,
                                               const float* __restrict__ Ae,
                                               const int* __restrict__ es,
                                               const int* __restrict__ et,
                                               const short* __restrict__ fH,
                                               const short* __restrict__ fL,
                                               const float* __restrict__ lb,
                                               float* __restrict__ Hdump,
                                               float* __restrict__ Mdump) {
    __shared__ __align__(16) short zTh[ZROWS * 16];
    __shared__ __align__(16) short zTl[ZROWS * 16];
    __shared__ float stage[32 * STG];
    const int tid = threadIdx.x, e = blockIdx.x;
    const int s = es[e], t = et[e];
    const int lane = tid & 63, wid = tid >> 6;
    const int cotile = wid >> 1, ph = wid & 1;
    const int colp = lane & 15, ciq = (lane >> 4) & 1, th = lane >> 5;

    const short8* f8H = (const short8*)fH;
    const short8* f8L = (const short8*)fL;
    short8 wah[5], wal[5];
#pragma unroll
    for (int ks = 0; ks < 5; ks++) {
        wah[ks] = f8H[(ks * 2 + cotile) * 64 + lane];
        wal[ks] = f8L[(ks * 2 + cotile) * 64 + lane];
    }
    for (int i = tid; i < (ZROWS * 16) / 2; i += 256) {
        ((unsigned int*)zTh)[i] = 0u; ((unsigned int*)zTl)[i] = 0u;
    }
    __syncthreads();
    const float* an = An + (size_t)s * NPAD;
    const float* ae = Ae + (size_t)t * NPAD;
    for (int i = tid; i < TILE; i += 256) {
        int ci = i / 126, pos = i - ci * 126;
        int y = pos / 18, x = pos - y * 18;
        int jp = ci * (HH * RPAD) + y * RPAD + x;
        float v = an[jp] * ae[jp];
        v = v > 0.f ? v : expm1f(v);
        unsigned short hi = f2bf(v);
        unsigned short lo = f2bf(v - bf2f(hi));
        int o = (20 + y * 19 + x) * 16 + ci;
        zTh[o] = (short)hi; zTl[o] = (short)lo;
    }
    __syncthreads();
    f32x4 acc[4];
    MFMA_CORE(acc)
#pragma unroll
    for (int pt = 0; pt < 4; pt++) {
        int p = (ph * 4 + pt) * 16 + colp;
        int co0 = cotile * 16 + (lane >> 4) * 4;
#pragma unroll
        for (int r = 0; r < 4; r++) stage[(co0 + r) * STG + p] = acc[pt][r];
    }
    __syncthreads();
    for (int i = tid; i < 32 * 126; i += 256) {
        int co = i / 126, p = i - co * 126;
        Hdump[(size_t)e * 4032 + i] = stage[co * STG + p];
    }
    for (int i = tid; i < TILE; i += 256) {
        int co = i / 126, p = i - co * 126;
        float hf = stage[co * STG + p] + lb[co];
        float hc = stage[(co + 16) * STG + p] + lb[co + 16];
        Mdump[(size_t)e * TILE + i] = (1.f / (1.f + expf(-hf))) * sp_f(hc);
    }
}

// fp32 in-kernel reference compare: dc3 = msg verdict, dc4 = raw-h verdict
__global__ __launch_bounds__(256) void k_check34(const float* __restrict__ An,
                                                 const float* __restrict__ Ae,
                                                 const int* __restrict__ es,
                                                 const int* __restrict__ et,
                                                 const float* __restrict__ lw,
                                                 const float* __restrict__ lb,
                                                 const float* __restrict__ Hdump,
                                                 const float* __restrict__ Mdump,
                                                 int* __restrict__ dc3,
                                                 int* __restrict__ dc4) {
    __shared__ float z[TILE];
    __shared__ int r3[256], r4[256];
    int e = blockIdx.x, tid = threadIdx.x;
    int s = es[e], t = et[e];
    const float* an = An + (size_t)s * NPAD;
    const float* ae = Ae + (size_t)t * NPAD;
    for (int i = tid; i < TILE; i += 256) {
        int ci = i / 126, pos = i - ci * 126;
        int y = pos / 18, x = pos - y * 18;
        int jp = ci * (HH * RPAD) + y * RPAD + x;
        float v = an[jp] * ae[jp];
        z[i] = v > 0.f ? v : expm1f(v);
    }
    __syncthreads();
    int c3 = 0, c4 = 0;
    for (int i = tid; i < TILE; i += 256) {
        int co = i / 126, p = i - co * 126, y = p / 18, x = p - y * 18;
        float hf = 0.f, hc = 0.f;
        for (int ci = 0; ci < 16; ci++) {
#pragma unroll
            for (int dy = 0; dy < 3; dy++) {
                int yy = y + dy - 1; if ((unsigned)yy >= 7u) continue;
#pragma unroll
                for (int dx = 0; dx < 3; dx++) {
                    int xx = x + dx - 1; if ((unsigned)xx >= 18u) continue;
                    float zv = z[ci * 126 + yy * 18 + xx];
                    hf = fmaf(zv, lw[(co * 16 + ci) * 9 + dy * 3 + dx], hf);
                    hc = fmaf(zv, lw[((co + 16) * 16 + ci) * 9 + dy * 3 + dx], hc);
                }
            }
        }
        float hrf = Hdump[(size_t)e * 4032 + co * 126 + p];
        float hrc = Hdump[(size_t)e * 4032 + (co + 16) * 126 + p];
        float d4 = fmaxf(fabsf(hrf - hf), fabsf(hrc - hc));
        if (d4 != d4) c4 = max(c4, 5); else if (d4 > 1e-2f) c4 = max(c4, 3);
        float mref = (1.f / (1.f + expf(-(hf + lb[co])))) * sp_f(hc + lb[co + 16]);
        float d3 = fabsf(Mdump[(size_t)e * TILE + i] - mref);
        if (d3 != d3) c3 = max(c3, 5); else if (d3 > 1e-2f) c3 = max(c3, 3);
    }
    r3[tid] = c3; r4[tid] = c4;
    __syncthreads();
    for (int off = 128; off > 0; off >>= 1) {
        if (tid < off) { r3[tid] = max(r3[tid], r3[tid + off]);
                         r4[tid] = max(r4[tid], r4[tid + off]); }
        __syncthreads();
    }
    if (tid == 0) { atomicMax(dc3, r3[0]); atomicMax(dc4, r4[0]); }
}

// verdict spins (distinct names -> readable rows); k_cal calibrates cyc/iter
__global__ void k_cal(const int* dc) { spin_k(SPIN_UNIT); }
__global__ void k_v1(const int* dc) { spin_k(dc[0] * SPIN_UNIT); }
__global__ void k_v2(const int* dc) { spin_k(dc[1] * SPIN_UNIT); }
__global__ void k_v3(const int* dc) { spin_k(dc[2] * SPIN_UNIT); }
__global__ void k_v4(const int* dc) { spin_k(dc[3] * SPIN_UNIT); }

// ---------------- BN statistics (double accumulation) -----------------------
template <int C, int S>
__global__ void k_bn_stats(const float* __restrict__ X, double* __restrict__ acc, int M) {
    int c = blockIdx.y, tid = threadIdx.x;
    double s1 = 0.0, s2 = 0.0;
    for (int m = blockIdx.x; m < M; m += gridDim.x) {
        const float* xr = &X[((size_t)m * C + c) * S];
        for (int s = tid; s < S; s += blockDim.x) {
            float v = xr[s];
            s1 += v; s2 += (double)v * v;
        }
    }
    __shared__ double sh1[256], sh2[256];
    sh1[tid] = s1; sh2[tid] = s2;
    __syncthreads();
    for (int off = blockDim.x >> 1; off > 0; off >>= 1) {
        if (tid < off) { sh1[tid] += sh1[tid + off]; sh2[tid] += sh2[tid + off]; }
        __syncthreads();
    }
    if (tid == 0) {
        unsafeAtomicAdd(&acc[2 * c], sh1[0]);
        unsafeAtomicAdd(&acc[2 * c + 1], sh2[0]);
    }
}

__global__ void k_bn_fin(const double* __restrict__ acc, const float* __restrict__ g,
                         const float* __restrict__ b, double invn,
                         float* __restrict__ scl, float* __restrict__ shf) {
    int c = threadIdx.x;
    if (c < 16) {
        double m = acc[2 * c] * invn;
        double v = acc[2 * c + 1] * invn - m * m;
        double s = (double)g[c] / sqrt(v + 1e-5);
        scl[c] = (float)s;
        shf[c] = (float)((double)b[c] - s * m);
    }
}

__global__ __launch_bounds__(256) void k_bn_res(float* __restrict__ atom,
                                                const float* __restrict__ outb,
                                                const float* __restrict__ scl,
                                                const float* __restrict__ shf) {
    __shared__ float sc[16], sh[16];
    int tid = threadIdx.x;
    if (tid < 16) { sc[tid] = scl[tid]; sh[tid] = shf[tid]; }
    __syncthreads();
    const long total = (long)NN * CC * PP;
    for (long i = (long)blockIdx.x * blockDim.x + tid; i < total;
         i += (long)gridDim.x * blockDim.x) {
        int c = (int)((i / PP) & 15);
        atom[i] += sc[c] * outb[i] + sh[c];
    }
}

// ---------------- mean pooling over graphs (atomic) -------------------------
__global__ __launch_bounds__(256) void k_pool(const float* __restrict__ atom,
                                              const int* __restrict__ gi,
                                              float* __restrict__ crys) {
    int n = blockIdx.x;
    int g = gi[n];
    const float* a = &atom[(size_t)n * CC * PP];
    float* cr = &crys[(size_t)g * CC * PP];
    for (int i = threadIdx.x; i < CC * PP; i += 256) unsafeAtomicAdd(&cr[i], a[i]);
}

// ---------------- conv_to_fc ------------------------------------------------
__global__ __launch_bounds__(256) void k_ctf(const float* __restrict__ crys,
                                             const int* __restrict__ counts,
                                             const float* __restrict__ w,
                                             const float* __restrict__ b,
                                             float* __restrict__ flat) {
    __shared__ float tile[CC * PP];
    __shared__ float ws[CC * CC * 9];
    __shared__ float bs[CC];
    int g = blockIdx.x, tid = threadIdx.x;
    float cnt = (float)counts[g];
    for (int i = tid; i < CC * PP; i += 256) tile[i] = crys[(size_t)g * CC * PP + i] / cnt;
    for (int i = tid; i < CC * CC * 9; i += 256) ws[i] = w[i];
    if (tid < CC) bs[tid] = b[tid];
    __syncthreads();
    for (int i = tid; i < CC * PP; i += 256) {
        int co = i / PP, p = i - co * PP, y = p / WW, x = p - (p / WW) * WW;
        float acc = bs[co];
#pragma unroll
        for (int dy = 0; dy < 3; dy++) {
            int yy = y + dy - 1; if ((unsigned)yy >= (unsigned)HH) continue;
#pragma unroll
            for (int dx = 0; dx < 3; dx++) {
                int xx = x + dx - 1; if ((unsigned)xx >= (unsigned)WW) continue;
                int zoff = yy * WW + xx, tap = dy * 3 + dx;
                const float* tp = &tile[zoff];
                const float* wp = &ws[co * 144 + tap];
#pragma unroll
                for (int ci = 0; ci < CC; ci++) acc += tp[ci * PP] * wp[ci * 9];
            }
        }
        flat[(size_t)g * CC * PP + i] = sp_f(acc);
    }
}

// ---------------- space branch ----------------------------------------------
__global__ __launch_bounds__(256) void k_space1(const int* __restrict__ nsites,
                                                const int* __restrict__ sgs,
                                                const float* __restrict__ w1,
                                                const float* __restrict__ b1,
                                                const float* __restrict__ w2,
                                                const float* __restrict__ b2,
                                                const float* __restrict__ cw,
                                                const float* __restrict__ cb,
                                                float* __restrict__ sembp) {
    __shared__ float outer[256];
    __shared__ float row[16], col[16];
    __shared__ float cws[144], cbs[16];
    int g = blockIdx.x, tid = threadIdx.x;
    if (tid < 16) {
        float ns = (float)nsites[g], sg = (float)sgs[g];
        row[tid] = ns * w1[2 * tid] + sg * w1[2 * tid + 1] + b1[tid];
        col[tid] = ns * w2[2 * tid] + sg * w2[2 * tid + 1] + b2[tid];
        cbs[tid] = cb[tid];
    }
    if (tid >= 64 && tid < 64 + 144) cws[tid - 64] = cw[tid - 64];
    __syncthreads();
    outer[tid] = row[tid >> 4] * col[tid & 15];
    __syncthreads();
    for (int i = tid; i < 16 * 256; i += 256) {
        int c = i >> 8, p = i & 255, y = p >> 4, x = p & 15;
        float acc = cbs[c];
#pragma unroll
        for (int dy = 0; dy < 3; dy++) {
            int yy = y + dy - 1; if ((unsigned)yy >= 16u) continue;
#pragma unroll
            for (int dx = 0; dx < 3; dx++) {
                int xx = x + dx - 1; if ((unsigned)xx >= 16u) continue;
                acc += outer[yy * 16 + xx] * cws[c * 9 + dy * 3 + dx];
            }
        }
        sembp[(size_t)g * 4096 + i] = acc;
    }
}

__global__ __launch_bounds__(256) void k_bn_sp256(const float* __restrict__ X,
                                                  float* __restrict__ Y,
                                                  const float* __restrict__ scl,
                                                  const float* __restrict__ shf) {
    __shared__ float sc[16], sh[16];
    if (threadIdx.x < 16) { sc[threadIdx.x] = scl[threadIdx.x]; sh[threadIdx.x] = shf[threadIdx.x]; }
    __syncthreads();
    int total = BB * 16 * 256;
    for (int i = blockIdx.x * blockDim.x + threadIdx.x; i < total;
         i += gridDim.x * blockDim.x) {
        int c = (i >> 8) & 15;
        Y[i] = sp_f(sc[c] * X[i] + sh[c]);
    }
}

__global__ __launch_bounds__(256) void k_space_conv(const float* __restrict__ X,
                                                    const float* __restrict__ w,
                                                    const float* __restrict__ b,
                                                    float* __restrict__ Y) {
    __shared__ float tile[16 * 256];
    __shared__ float ws[2304], bs[16];
    int g = blockIdx.x, tid = threadIdx.x;
    for (int i = tid; i < 4096; i += 256) tile[i] = X[(size_t)g * 4096 + i];
    for (int i = tid; i < 2304; i += 256) ws[i] = w[i];
    if (tid < 16) bs[tid] = b[tid];
    __syncthreads();
    for (int i = tid; i < 4096; i += 256) {
        int c = i >> 8, p = i & 255, y = p >> 4, x = p & 15;
        float acc = bs[c];
#pragma unroll
        for (int dy = 0; dy < 3; dy++) {
            int yy = y + dy - 1; if ((unsigned)yy >= 16u) continue;
#pragma unroll
            for (int dx = 0; dx < 3; dx++) {
                int xx = x + dx - 1; if ((unsigned)xx >= 16u) continue;
                int tap = dy * 3 + dx;
                const float* wp = &ws[c * 144 + tap];
                const float* tp = &tile[yy * 16 + xx];
#pragma unroll
                for (int ci = 0; ci < 16; ci++) acc += tp[ci * 256] * wp[ci * 9];
            }
        }
        Y[(size_t)g * 4096 + i] = acc;
    }
}

__global__ __launch_bounds__(256) void k_space_tail(const float* __restrict__ ypre,
                                                    const float* __restrict__ scl,
                                                    const float* __restrict__ shf,
                                                    const float* __restrict__ fc3w,
                                                    const float* __restrict__ fc3b,
                                                    float* __restrict__ sout) {
    __shared__ float red[256];
    int g = blockIdx.x, tid = threadIdx.x;
    float val = 0.f;
    if (tid < 144) {
        int c = tid / 9, cell = tid - c * 9, py = cell / 3, px = cell - py * 3;
        float sc = scl[c], sh = shf[c];
        float mx = -INFINITY;
        const float* base = &ypre[((size_t)g * 16 + c) * 256];
        for (int yy = py * 5; yy < py * 5 + 5; yy++)
            for (int xx = px * 5; xx < px * 5 + 5; xx++)
                mx = fmaxf(mx, sc * base[yy * 16 + xx] + sh);
        val = sp_f(mx) * fc3w[tid];
    }
    red[tid] = val;
    __syncthreads();
    for (int off = 128; off > 0; off >>= 1) {
        if (tid < off) red[tid] += red[tid + off];
        __syncthreads();
    }
    if (tid == 0) sout[g] = red[0] + fc3b[0];
}

// ---------------- FC head ---------------------------------------------------
__global__ __launch_bounds__(256) void k_head(const float* __restrict__ flat,
                                              const float* __restrict__ fc1w,
                                              const float* __restrict__ fc1b,
                                              const float* __restrict__ fc2w,
                                              const float* __restrict__ fc2b,
                                              const float* __restrict__ regw,
                                              const float* __restrict__ regb,
                                              const float* __restrict__ sout,
                                              const float* __restrict__ eps,
                                              float* __restrict__ out) {
    int g = blockIdx.x, tid = threadIdx.x;
    __shared__ float h1[32], h2[32];
    int o = tid >> 3, r = tid & 7;
    float part = 0.f;
    const float* fr = &flat[(size_t)g * 2016];
    const float* wr = &fc1w[(size_t)o * 2016];
    for (int j = r; j < 2016; j += 8) part += fr[j] * wr[j];
    part += __shfl_down(part, 4, 8);
    part += __shfl_down(part, 2, 8);
    part += __shfl_down(part, 1, 8);
    if (r == 0) h1[o] = sp_f(part + fc1b[o]);
    __syncthreads();
    if (tid < 32) {
        float a = fc2b[tid];
        for (int j = 0; j < 32; j++) a += h1[j] * fc2w[tid * 32 + j];
        h2[tid] = sp_f(a);
    }
    __syncthreads();
    if (tid == 0) {
        float a = regb[0];
        for (int j = 0; j < 32; j++) a += h2[j] * regw[j];
        out[g] = a + eps[0] * sout[g];
    }
}

// ===========================================================================
extern "C" void kernel_launch(void* const* d_in, const int* in_sizes, int n_in,
                              void* d_out, int out_size, void* d_ws, size_t ws_size,
                              hipStream_t stream) {
    const float* nodes   = (const float*)d_in[0];
    const int*   es      = (const int*)d_in[1];
    const int*   et      = (const int*)d_in[2];
    const int*   gi      = (const int*)d_in[3];
    const int*   cnt     = (const int*)d_in[4];
    const int*   nsites  = (const int*)d_in[5];
    const int*   sgs     = (const int*)d_in[6];
    const float* emb_w   = (const float*)d_in[7];
    const float* emb_b   = (const float*)d_in[8];
    const float* cl_nw   = (const float*)d_in[9];
    const float* cl_ew   = (const float*)d_in[10];
    const float* cl_lw   = (const float*)d_in[11];
    const float* cl_lb   = (const float*)d_in[12];
    const float* cl_bg   = (const float*)d_in[13];
    const float* cl_bb   = (const float*)d_in[14];
    const float* se_w1   = (const float*)d_in[15];
    const float* se_b1   = (const float*)d_in[16];
    const float* se_w2   = (const float*)d_in[17];
    const float* se_b2   = (const float*)d_in[18];
    const float* se_cw   = (const float*)d_in[19];
    const float* se_cb   = (const float*)d_in[20];
    const float* se_bg   = (const float*)d_in[21];
    const float* se_bb   = (const float*)d_in[22];
    const float* sf_cw   = (const float*)d_in[23];
    const float* sf_cb   = (const float*)d_in[24];
    const float* sf_bg   = (const float*)d_in[25];
    const float* sf_bb   = (const float*)d_in[26];
    const float* ctf_w   = (const float*)d_in[27];
    const float* ctf_b   = (const float*)d_in[28];
    const float* fc1_w   = (const float*)d_in[29];
    const float* fc1_b   = (const float*)d_in[30];
    const float* fc2_w   = (const float*)d_in[31];
    const float* fc2_b   = (const float*)d_in[32];
    const float* reg_w   = (const float*)d_in[33];
    const float* reg_b   = (const float*)d_in[34];
    const float* fc3_w   = (const float*)d_in[35];
    const float* fc3_b   = (const float*)d_in[36];
    const float* eps     = (const float*)d_in[37];
    float* out = (float*)d_out;

    const size_t ATOM_B = (size_t)NN * TILE * sizeof(float);   // 33 MB
    const size_t PAD_B  = (size_t)NN * NPAD * sizeof(float);   // 36.7 MB
    char* ws = (char*)d_ws;
    float*  atom  = (float*)ws;              ws += ATOM_B;
    float*  An    = (float*)ws;              ws += PAD_B;
    float*  Ae    = (float*)ws;              ws += PAD_B;
    float*  outb  = (float*)ws;              ws += ATOM_B;
    double* acc   = (double*)ws;             ws += 256;
    float*  scl   = (float*)ws;              ws += 256;
    float*  shf   = (float*)ws;              ws += 256;
    float*  sout  = (float*)ws;              ws += 256;
    float*  nwT   = (float*)ws;              ws += 4608 * sizeof(float);
    float*  lwT   = (float*)ws;              ws += 4608 * sizeof(float);
    short*  efH   = (short*)ws;              ws += 5120 * sizeof(short);
    short*  efL   = (short*)ws;              ws += 5120 * sizeof(short);
    int*    dc    = (int*)ws;                ws += 256;
    float*  P1    = (float*)ws;              ws += 256 * sizeof(float);
    float*  P2    = (float*)ws;              ws += 256 * sizeof(float);
    float*  Hdump = (float*)ws;              ws += 4 * 4032 * sizeof(float);
    float*  Mdump = (float*)ws;              ws += 4 * TILE * sizeof(float);
    float*  crys  = (float*)ws;              ws += (size_t)BB * TILE * sizeof(float);
    float*  flat  = (float*)ws;              ws += (size_t)BB * TILE * sizeof(float);
    float*  sembp = (float*)ws;              ws += (size_t)BB * 16 * 256 * sizeof(float);
    float*  semb  = (float*)ws;              ws += (size_t)BB * 16 * 256 * sizeof(float);
    float*  ypre  = (float*)ws;              ws += (size_t)BB * 16 * 256 * sizeof(float);

    // ---- embedding
    k_embed<<<NN, 256, 0, stream>>>(nodes, emb_w, emb_b, atom);

    // ---- 3 conv layers (R3 production path)
    for (int l = 0; l < 3; l++) {
        const float* nw = cl_nw + (size_t)l * CC * CC * 9;
        const float* ew = cl_ew + (size_t)l * CC * CC * 9;
        const float* lw = cl_lw + (size_t)l * 32 * CC * 9;
        const float* lb = cl_lb + (size_t)l * 32;
        const float* bg = cl_bg + (size_t)l * 16;
        const float* bb = cl_bb + (size_t)l * 16;

        k_wT2<<<9, 256, 0, stream>>>(nw, ew, nwT);
        k_wT<<<18, 256, 0, stream>>>(lw, lwT);
        k_node_conv2<<<NN / 2, 256, 0, stream>>>(atom, nwT, An, Ae);

        if (l == 0) {
            // ---- MFMA probe suite (verdicts encoded as k_v* spin durations,
            // in units of k_cal's duration; absent spin = probe passed)
            k_wprep_edge<<<20, 256, 0, stream>>>(lw, efH, efL);
            hipMemsetAsync(dc, 0, 16, stream);
            k_probe1<<<1, 64, 0, stream>>>(P1);
            k_probe2<<<1, 64, 0, stream>>>(P2);
            k_mfma4<<<4, 256, 0, stream>>>(An, Ae, es, et, efH, efL, lb,
                                           Hdump, Mdump);
            k_check1<<<1, 256, 0, stream>>>(P1, dc + 0);
            k_check2<<<1, 256, 0, stream>>>(P2, dc + 1);
            k_check34<<<4, 256, 0, stream>>>(An, Ae, es, et, lw, lb,
                                             Hdump, Mdump, dc + 2, dc + 3);
            k_cal<<<1, 64, 0, stream>>>(dc);
            k_v1<<<1, 64, 0, stream>>>(dc);
            k_v2<<<1, 64, 0, stream>>>(dc);
            k_v3<<<1, 64, 0, stream>>>(dc);
            k_v4<<<1, 64, 0, stream>>>(dc);
        }

        hipMemcpyAsync(outb, atom, ATOM_B, hipMemcpyDeviceToDevice, stream);
        k_edge<<<EE / 2, 256, 0, stream>>>(An, Ae, es, et, lwT, lb, outb);
        hipMemsetAsync(acc, 0, 16 * 2 * sizeof(double), stream);
        k_bn_stats<16, 126><<<dim3(64, 16), 128, 0, stream>>>(outb, acc, NN);
        k_bn_fin<<<1, 16, 0, stream>>>(acc, bg, bb, 1.0 / ((double)NN * PP), scl, shf);
        k_bn_res<<<2048, 256, 0, stream>>>(atom, outb, scl, shf);
    }

    // ---- space branch
    k_space1<<<BB, 256, 0, stream>>>(nsites, sgs, se_w1, se_b1, se_w2, se_b2,
                                     se_cw, se_cb, sembp);
    hipMemsetAsync(acc, 0, 16 * 2 * sizeof(double), stream);
    k_bn_stats<16, 256><<<dim3(8, 16), 256, 0, stream>>>(sembp, acc, BB);
    k_bn_fin<<<1, 16, 0, stream>>>(acc, se_bg, se_bb, 1.0 / (BB * 256.0), scl, shf);
    k_bn_sp256<<<256, 256, 0, stream>>>(sembp, semb, scl, shf);
    k_space_conv<<<BB, 256, 0, stream>>>(semb, sf_cw, sf_cb, ypre);
    hipMemsetAsync(acc, 0, 16 * 2 * sizeof(double), stream);
    k_bn_stats<16, 256><<<dim3(8, 16), 256, 0, stream>>>(ypre, acc, BB);
    k_bn_fin<<<1, 16, 0, stream>>>(acc, sf_bg, sf_bb, 1.0 / (BB * 256.0), scl, shf);
    k_space_tail<<<BB, 256, 0, stream>>>(ypre, scl, shf, fc3_w, fc3_b, sout);

    // ---- pooling + conv_to_fc + head
    hipMemsetAsync(crys, 0, (size_t)BB * TILE * sizeof(float), stream);
    k_pool<<<NN, 256, 0, stream>>>(atom, gi, crys);
    k_ctf<<<BB, 256, 0, stream>>>(crys, cnt, ctf_w, ctf_b, flat);
    k_head<<<BB, 256, 0, stream>>>(flat, fc1_w, fc1_b, fc2_w, fc2_b,
                                   reg_w, reg_b, sout, eps, out);
}

// Round 7
// 5793.363 us; speedup vs baseline: 3.0678x; 3.0678x over previous
//
#include <hip/hip_runtime.h>
#include <math.h>

#define HH 7
#define WW 18
#define PP 126        // HH*WW
#define CC 16
#define NN 4096
#define EE 16384
#define BB 64
#define TILE 2016               // CC*PP, std layout
#define ZT 2880                 // 16*9*20 haloed tile (An/Ae layout)
#define ZROWS 172               // MFMA probe LDS tile rows
#define STG 132
#define SPIN_BIG 1500000

typedef __attribute__((ext_vector_type(8))) short short8;
typedef __attribute__((ext_vector_type(4))) float f32x4;

__device__ __forceinline__ float sp_f(float x) {
    // softplus, JAX-stable form: max(x,0)+log1p(exp(-|x|))
    return fmaxf(x, 0.f) + log1pf(expf(-fabsf(x)));
}
__device__ __forceinline__ unsigned short f2bf(float f) {
    unsigned int u = __builtin_bit_cast(unsigned int, f);
    unsigned int r = u + 0x7fffu + ((u >> 16) & 1u);   // RNE
    return (unsigned short)(r >> 16);
}
__device__ __forceinline__ float bf2f(unsigned short h) {
    unsigned int u = ((unsigned int)h) << 16;
    return __builtin_bit_cast(float, u);
}
__device__ __forceinline__ void spin_k(int kiter) {
    if (kiter <= 0) return;
    float acc = (float)threadIdx.x;
    for (int i = 0; i < kiter; i++) acc = fmaf(acc, 1.0000001f, 0.125f);
    asm volatile("" :: "v"(acc));
}

// ---------------- fp32 weight transposes -> [tap][ci][co16][2] --------------
__global__ void k_wT(const float* __restrict__ w, float* __restrict__ wT) {
    int i = blockIdx.x * 256 + threadIdx.x;
    if (i < 32 * 144) {
        int co = i / 144, r = i - co * 144, ci = r / 9, tap = r - ci * 9;
        int half = co >> 4, coo = co & 15;
        wT[((tap * 16 + ci) * 16 + coo) * 2 + half] = w[i];
    }
}
__global__ void k_wT2(const float* __restrict__ wN, const float* __restrict__ wE,
                      float* __restrict__ wT) {
    int i = blockIdx.x * 256 + threadIdx.x;
    if (i < 16 * 144) {
        int co = i / 144, r = i - co * 144, ci = r / 9, tap = r - ci * 9;
        wT[((tap * 16 + ci) * 16 + co) * 2 + 0] = wN[i];
        wT[((tap * 16 + ci) * 16 + co) * 2 + 1] = wE[i];
    }
}

// ---------------- embedding -------------------------------------------------
__global__ __launch_bounds__(256) void k_embed(const float* __restrict__ nodes,
                                               const float* __restrict__ w,
                                               const float* __restrict__ b,
                                               float* __restrict__ atom) {
    __shared__ float tile[PP];
    __shared__ float ws[CC * 9];
    __shared__ float bs[CC];
    int n = blockIdx.x, tid = threadIdx.x;
    for (int i = tid; i < PP; i += 256) tile[i] = nodes[n * PP + i];
    for (int i = tid; i < CC * 9; i += 256) ws[i] = w[i];
    if (tid < CC) bs[tid] = b[tid];
    __syncthreads();
    for (int i = tid; i < CC * PP; i += 256) {
        int c = i / PP, p = i - c * PP, y = p / WW, x = p - (p / WW) * WW;
        float acc = bs[c];
#pragma unroll
        for (int dy = 0; dy < 3; dy++) {
            int yy = y + dy - 1; if ((unsigned)yy >= (unsigned)HH) continue;
#pragma unroll
            for (int dx = 0; dx < 3; dx++) {
                int xx = x + dx - 1; if ((unsigned)xx >= (unsigned)WW) continue;
                acc += tile[yy * WW + xx] * ws[c * 9 + dy * 3 + dx];
            }
        }
        atom[(size_t)n * CC * PP + i] = sp_f(acc);
    }
}

// ---------------- branch-free fp32 conv core (proven R5) --------------------
// zt: haloed tile [16 ci][9 rows][20 cols], halos zero. ws: [9][16][16][2].
__device__ __forceinline__ void conv_body(const float* zt,
                                          const float (*ws)[16][16][2],
                                          int co, int y, float* hA, float* hB) {
    for (int ci = 0; ci < 16; ci++) {
        const float* zb = zt + ci * 180 + y * 20;
#pragma unroll
        for (int dy = 0; dy < 3; dy++) {
            const float* zr = zb + dy * 20;
            float4 q0 = *(const float4*)&zr[0];
            float4 q1 = *(const float4*)&zr[4];
            float4 q2 = *(const float4*)&zr[8];
            float4 q3 = *(const float4*)&zr[12];
            float4 q4 = *(const float4*)&zr[16];
            float r[20];
            r[0]=q0.x; r[1]=q0.y; r[2]=q0.z; r[3]=q0.w;
            r[4]=q1.x; r[5]=q1.y; r[6]=q1.z; r[7]=q1.w;
            r[8]=q2.x; r[9]=q2.y; r[10]=q2.z; r[11]=q2.w;
            r[12]=q3.x; r[13]=q3.y; r[14]=q3.z; r[15]=q3.w;
            r[16]=q4.x; r[17]=q4.y; r[18]=q4.z; r[19]=q4.w;
            float2 w0 = *(const float2*)&ws[dy * 3 + 0][ci][co][0];
            float2 w1 = *(const float2*)&ws[dy * 3 + 1][ci][co][0];
            float2 w2 = *(const float2*)&ws[dy * 3 + 2][ci][co][0];
#pragma unroll
            for (int x = 0; x < 18; x++) {
                hA[x] = fmaf(r[x],     w0.x, hA[x]);
                hA[x] = fmaf(r[x + 1], w1.x, hA[x]);
                hA[x] = fmaf(r[x + 2], w2.x, hA[x]);
                hB[x] = fmaf(r[x],     w0.y, hB[x]);
                hB[x] = fmaf(r[x + 1], w1.y, hB[x]);
                hB[x] = fmaf(r[x + 2], w2.y, hB[x]);
            }
        }
    }
}

// ------------- per-node dual conv, 2 nodes/block; An/Ae OUT in halo layout --
__global__ __launch_bounds__(256) void k_node_conv2(const float* __restrict__ atom,
                                                    const float* __restrict__ wT,
                                                    float* __restrict__ An,
                                                    float* __restrict__ Ae) {
    __shared__ __align__(16) float zf[2 * ZT];
    __shared__ __align__(16) float ws[9][16][16][2];
    int tid = threadIdx.x;
    int n0 = blockIdx.x * 2;
    for (int i = tid; i < 2 * ZT; i += 256) {
        int e2 = i / ZT, r = i - e2 * ZT;
        int ci = r / 180, rr = r - ci * 180;
        int yy = rr / 20, xx = rr - yy * 20;
        float v = 0.f;
        if ((unsigned)(yy - 1) < 7u && (unsigned)(xx - 1) < 18u)
            v = atom[(size_t)(n0 + e2) * TILE + ci * 126 + (yy - 1) * 18 + (xx - 1)];
        zf[i] = v;
    }
    for (int i = tid; i < 4608; i += 256) ((float*)ws)[i] = wT[i];
    __syncthreads();
    int grp = tid >> 7, lt = tid & 127;
    bool act = lt < 112;
    int co = lt & 15, y = lt >> 4;
    float hA[18], hB[18];
#pragma unroll
    for (int x = 0; x < 18; x++) { hA[x] = 0.f; hB[x] = 0.f; }
    if (act) conv_body(&zf[grp * ZT], ws, co, y, hA, hB);
    __syncthreads();
    // zero entire buffer once (halo zeros for output), then stage hA (node out)
    for (int i = tid; i < 2 * ZT; i += 256) zf[i] = 0.f;
    __syncthreads();
    int base = grp * ZT + co * 180 + (y + 1) * 20 + 1;
    if (act) {
#pragma unroll
        for (int x = 0; x < 18; x++) zf[base + x] = hA[x];
    }
    __syncthreads();
    for (int i = tid; i < 2 * (ZT / 4); i += 256) {
        int e2 = i / (ZT / 4), j = i - e2 * (ZT / 4);
        ((float4*)&An[(size_t)(n0 + e2) * ZT])[j] = ((const float4*)zf)[i];
    }
    __syncthreads();
    // interior fully rewritten by same threads; halos still zero
    if (act) {
#pragma unroll
        for (int x = 0; x < 18; x++) zf[base + x] = hB[x];
    }
    __syncthreads();
    for (int i = tid; i < 2 * (ZT / 4); i += 256) {
        int e2 = i / (ZT / 4), j = i - e2 * (ZT / 4);
        ((float4*)&Ae[(size_t)(n0 + e2) * ZT])[j] = ((const float4*)zf)[i];
    }
}

// ---------------- per-edge conv, 2 edges/block; An/Ae IN halo layout --------
__global__ __launch_bounds__(256) void k_edge(const float* __restrict__ An,
                                              const float* __restrict__ Ae,
                                              const int* __restrict__ es,
                                              const int* __restrict__ et,
                                              const float* __restrict__ wT,
                                              const float* __restrict__ lb,
                                              float* __restrict__ outb) {
    __shared__ __align__(16) float zf[2 * ZT];
    __shared__ __align__(16) float ws[9][16][16][2];
    int tid = threadIdx.x;
    int e0 = blockIdx.x * 2;
    int s0 = es[e0], t0 = et[e0], s1 = es[e0 + 1], t1 = et[e0 + 1];
    // pure float4 load: halos 0*0 -> elu(0)=0 preserved
    for (int i = tid; i < 2 * (ZT / 4); i += 256) {
        int e2 = i / (ZT / 4), j = i - e2 * (ZT / 4);
        float4 a4 = ((const float4*)&An[(size_t)(e2 ? s1 : s0) * ZT])[j];
        float4 b4 = ((const float4*)&Ae[(size_t)(e2 ? t1 : t0) * ZT])[j];
        float4 res;
        res.x = a4.x * b4.x; res.x = res.x > 0.f ? res.x : expm1f(res.x);
        res.y = a4.y * b4.y; res.y = res.y > 0.f ? res.y : expm1f(res.y);
        res.z = a4.z * b4.z; res.z = res.z > 0.f ? res.z : expm1f(res.z);
        res.w = a4.w * b4.w; res.w = res.w > 0.f ? res.w : expm1f(res.w);
        ((float4*)zf)[i] = res;
    }
    for (int i = tid; i < 4608; i += 256) ((float*)ws)[i] = wT[i];
    __syncthreads();
    int grp = tid >> 7, lt = tid & 127;
    bool act = lt < 112;
    int co = lt & 15, y = lt >> 4;
    float hA[18], hB[18];
#pragma unroll
    for (int x = 0; x < 18; x++) { hA[x] = 0.f; hB[x] = 0.f; }
    if (act) conv_body(&zf[grp * ZT], ws, co, y, hA, hB);
    __syncthreads();
    // stage msg in std layout (zf dead), then coalesced atomic scatter
    float* msgL = zf;
    if (act) {
        float bf = lb[co], bc = lb[co + 16];
        int base = grp * TILE + co * 126 + y * 18;
#pragma unroll
        for (int x = 0; x < 18; x++) {
            float hfv = hA[x] + bf, hcv = hB[x] + bc;
            msgL[base + x] = (1.f / (1.f + expf(-hfv))) * sp_f(hcv);
        }
    }
    __syncthreads();
    for (int i = tid; i < 2 * TILE; i += 256) {
        int e2 = i / TILE, j = i - e2 * TILE;
        unsafeAtomicAdd(&outb[(size_t)(e2 ? s1 : s0) * TILE + j], msgL[i]);
    }
}

// ==================== MFMA self-calibration probe suite =====================
// flags[0]=pairing-valid(1 good), flags[1]=mismatch(1 bad), flags[2]=builtin-bad(1 bad)

// builtin sanity: A=B=1 -> all acc == 32.0
__global__ void k_probe1(int* __restrict__ flags) {
    short8 a, b;
#pragma unroll
    for (int j = 0; j < 8; j++) { a[j] = (short)0x3f80; b[j] = (short)0x3f80; }
    f32x4 c = {0.f, 0.f, 0.f, 0.f};
    c = __builtin_amdgcn_mfma_f32_16x16x32_bf16(a, b, c, 0, 0, 0);
    int bad = 0;
#pragma unroll
    for (int r = 0; r < 4; r++) if (!(fabsf(c[r] - 32.f) < 0.5f)) bad = 1;
    if (bad) atomicOr(&flags[2], 1);
}

// discover A<->B k-pairing: part[pa] = B-position paired with A-position pa.
// A-position (g,j): lane-group g=lane>>4, elem j. Row m probes pa=half*16+m.
__global__ void k_pairprobe(int* __restrict__ part, int* __restrict__ flags) {
    __shared__ float dump[2 * 256];
    __shared__ int psh[32], gsh[32];
    int lane = threadIdx.x;           // 64 threads
    int m = lane & 15, g = lane >> 4;
    short8 b;
#pragma unroll
    for (int j = 0; j < 8; j++) b[j] = (short)f2bf((float)(g * 8 + j + 1));
#pragma unroll
    for (int half = 0; half < 2; half++) {
        short8 a;
#pragma unroll
        for (int j = 0; j < 8; j++)
            a[j] = (g * 8 + j == half * 16 + m) ? (short)0x3f80 : (short)0;
        f32x4 c = {0.f, 0.f, 0.f, 0.f};
        c = __builtin_amdgcn_mfma_f32_16x16x32_bf16(a, b, c, 0, 0, 0);
#pragma unroll
        for (int r = 0; r < 4; r++)
            dump[half * 256 + (g * 4 + r) * 16 + m] = c[r];  // [row][col]
    }
    __syncthreads();
    if (lane < 32) {
        float v = dump[(lane >> 4) * 256 + (lane & 15) * 16 + 0];  // D[m][0]
        float rv = rintf(v);
        int iv = (int)rv - 1;
        int good = (fabsf(v - rv) < 0.25f && iv >= 0 && iv < 32) ? 1 : 0;
        psh[lane] = good ? iv : lane;
        gsh[lane] = good;
    }
    __syncthreads();
    if (lane == 0) {
        unsigned mask = 0; int ok = 1;
        for (int p = 0; p < 32; p++) { ok &= gsh[p]; mask |= (1u << psh[p]); }
        if (mask != 0xFFFFFFFFu) ok = 0;
        flags[0] = ok;
    }
    if (lane < 32) part[lane] = psh[lane];
}

// A-fragment pack THROUGH the discovered pairing. B staging lambda:
// B-position (g,j) holds z[ci=(g&1)*8+j][tap = ks*2 + (g>>1)].
__global__ void k_wprep_cal(const float* __restrict__ lw, const int* __restrict__ part,
                            short* __restrict__ fH, short* __restrict__ fL) {
    int idx = blockIdx.x * 256 + threadIdx.x;
    if (idx >= 5120) return;
    int j = idx & 7, lane = (idx >> 3) & 63, cotile = (idx >> 9) & 1, ks = idx >> 10;
    int g = lane >> 4;
    int co = cotile * 16 + (lane & 15);
    int pb = part[g * 8 + j];
    int gB = pb >> 3, jB = pb & 7;
    int ci = (gB & 1) * 8 + jB;
    int tap = ks * 2 + (gB >> 1);
    float v = (tap > 8) ? 0.f : lw[(co * 16 + ci) * 9 + tap];
    unsigned short hi = f2bf(v);
    unsigned short lo = f2bf(v - bf2f(hi));
    fH[idx] = (short)hi; fL[idx] = (short)lo;
}

#define MFMA_CORE(ACC)                                                          \
    int boff[5];                                                                \
    _Pragma("unroll")                                                           \
    for (int ks = 0; ks < 5; ks++) {                                            \
        int tap = ks * 2 + th; if (tap > 8) tap = 8;                            \
        boff[ks] = (tap / 3 - 1) * 19 + (tap - (tap / 3) * 3) - 1;              \
    }                                                                           \
    _Pragma("unroll")                                                           \
    for (int pt = 0; pt < 4; pt++) ACC[pt] = (f32x4){0.f, 0.f, 0.f, 0.f};       \
    _Pragma("unroll")                                                           \
    for (int pt = 0; pt < 4; pt++) {                                            \
        int p = (ph * 4 + pt) * 16 + colp;                                      \
        int y = 0, x = 0;                                                       \
        if (p < 126) { y = p / 18; x = p - y * 18; }                            \
        int bbase = (20 + y * 19 + x) * 16 + ciq * 8;                           \
        _Pragma("unroll")                                                       \
        for (int ks = 0; ks < 5; ks++) {                                        \
            short8 bh = *(const short8*)&zTh[bbase + boff[ks] * 16];            \
            short8 bl = *(const short8*)&zTl[bbase + boff[ks] * 16];            \
            ACC[pt] = __builtin_amdgcn_mfma_f32_16x16x32_bf16(wah[ks], bh, ACC[pt], 0, 0, 0); \
            ACC[pt] = __builtin_amdgcn_mfma_f32_16x16x32_bf16(wah[ks], bl, ACC[pt], 0, 0, 0); \
            ACC[pt] = __builtin_amdgcn_mfma_f32_16x16x32_bf16(wal[ks], bh, ACC[pt], 0, 0, 0); \
        }                                                                       \
    }

// calibrated edge-MFMA on 4 edges -> Mdump (msg values), halo An/Ae input
__global__ __launch_bounds__(256) void k_mfma4_cal(const float* __restrict__ An,
                                                   const float* __restrict__ Ae,
                                                   const int* __restrict__ es,
                                                   const int* __restrict__ et,
                                                   const short* __restrict__ fH,
                                                   const short* __restrict__ fL,
                                                   const float* __restrict__ lb,
                                                   float* __restrict__ Mdump) {
    __shared__ __align__(16) short zTh[ZROWS * 16];
    __shared__ __align__(16) short zTl[ZROWS * 16];
    __shared__ float stage[32 * STG];
    const int tid = threadIdx.x, e = blockIdx.x;
    const int s = es[e], t = et[e];
    const int lane = tid & 63, wid = tid >> 6;
    const int cotile = wid >> 1, ph = wid & 1;
    const int colp = lane & 15, ciq = (lane >> 4) & 1, th = lane >> 5;

    const short8* f8H = (const short8*)fH;
    const short8* f8L = (const short8*)fL;
    short8 wah[5], wal[5];
#pragma unroll
    for (int ks = 0; ks < 5; ks++) {
        wah[ks] = f8H[(ks * 2 + cotile) * 64 + lane];
        wal[ks] = f8L[(ks * 2 + cotile) * 64 + lane];
    }
    for (int i = tid; i < (ZROWS * 16) / 2; i += 256) {
        ((unsigned int*)zTh)[i] = 0u; ((unsigned int*)zTl)[i] = 0u;
    }
    __syncthreads();
    const float* an = An + (size_t)s * ZT;
    const float* ae = Ae + (size_t)t * ZT;
    for (int i = tid; i < TILE; i += 256) {
        int ci = i / 126, pos = i - ci * 126;
        int y = pos / 18, x = pos - y * 18;
        int jp = ci * 180 + (y + 1) * 20 + (x + 1);
        float v = an[jp] * ae[jp];
        v = v > 0.f ? v : expm1f(v);
        unsigned short hi = f2bf(v);
        unsigned short lo = f2bf(v - bf2f(hi));
        int o = (20 + y * 19 + x) * 16 + ci;
        zTh[o] = (short)hi; zTl[o] = (short)lo;
    }
    __syncthreads();
    f32x4 acc[4];
    MFMA_CORE(acc)
#pragma unroll
    for (int pt = 0; pt < 4; pt++) {
        int p = (ph * 4 + pt) * 16 + colp;
        int co0 = cotile * 16 + (lane >> 4) * 4;
#pragma unroll
        for (int r = 0; r < 4; r++) stage[(co0 + r) * STG + p] = acc[pt][r];
    }
    __syncthreads();
    for (int i = tid; i < TILE; i += 256) {
        int co = i / 126, p = i - co * 126;
        float hf = stage[co * STG + p] + lb[co];
        float hc = stage[(co + 16) * STG + p] + lb[co + 16];
        Mdump[(size_t)e * TILE + i] = (1.f / (1.f + expf(-hf))) * sp_f(hc);
    }
}

// fp32 reference compare (weights staged in LDS) -> flags[1] on mismatch
__global__ __launch_bounds__(256) void k_scmp(const float* __restrict__ An,
                                              const float* __restrict__ Ae,
                                              const int* __restrict__ es,
                                              const int* __restrict__ et,
                                              const float* __restrict__ lw,
                                              const float* __restrict__ lb,
                                              const float* __restrict__ Mdump,
                                              int* __restrict__ flags) {
    __shared__ float z[TILE];
    __shared__ float wl[4608];
    int e = blockIdx.x, tid = threadIdx.x;
    int s = es[e], t = et[e];
    const float* an = An + (size_t)s * ZT;
    const float* ae = Ae + (size_t)t * ZT;
    for (int i = tid; i < TILE; i += 256) {
        int ci = i / 126, pos = i - ci * 126;
        int y = pos / 18, x = pos - y * 18;
        int jp = ci * 180 + (y + 1) * 20 + (x + 1);
        float v = an[jp] * ae[jp];
        z[i] = v > 0.f ? v : expm1f(v);
    }
    for (int i = tid; i < 4608; i += 256) wl[i] = lw[i];
    __syncthreads();
    int bad = 0;
    for (int i = tid; i < TILE; i += 256) {
        int co = i / 126, p = i - co * 126, y = p / 18, x = p - y * 18;
        float hf = 0.f, hc = 0.f;
        for (int ci = 0; ci < 16; ci++) {
#pragma unroll
            for (int dy = 0; dy < 3; dy++) {
                int yy = y + dy - 1; if ((unsigned)yy >= 7u) continue;
#pragma unroll
                for (int dx = 0; dx < 3; dx++) {
                    int xx = x + dx - 1; if ((unsigned)xx >= 18u) continue;
                    float zv = z[ci * 126 + yy * 18 + xx];
                    hf = fmaf(zv, wl[(co * 16 + ci) * 9 + dy * 3 + dx], hf);
                    hc = fmaf(zv, wl[((co + 16) * 16 + ci) * 9 + dy * 3 + dx], hc);
                }
            }
        }
        float mref = (1.f / (1.f + expf(-(hf + lb[co])))) * sp_f(hc + lb[co + 16]);
        float d = fabsf(Mdump[(size_t)e * TILE + i] - mref);
        if (!(d < 1e-2f)) bad = 1;      // catches NaN too
    }
    if (bad) atomicOr(&flags[1], 1);
}

// verdict spins: fire ONLY on failure (absence from top-5 = pass)
__global__ void k_s1(const int* f) { spin_k(f[0] ? 0 : SPIN_BIG); }  // pairing invalid
__global__ void k_s2(const int* f) { spin_k(f[1] ? SPIN_BIG : 0); }  // MFMA mismatch
__global__ void k_s3(const int* f) { spin_k(f[2] ? SPIN_BIG : 0); }  // builtin broken

// ---------------- BN statistics (double accumulation) -----------------------
template <int C, int S>
__global__ void k_bn_stats(const float* __restrict__ X, double* __restrict__ acc, int M) {
    int c = blockIdx.y, tid = threadIdx.x;
    double s1 = 0.0, s2 = 0.0;
    for (int m = blockIdx.x; m < M; m += gridDim.x) {
        const float* xr = &X[((size_t)m * C + c) * S];
        for (int s = tid; s < S; s += blockDim.x) {
            float v = xr[s];
            s1 += v; s2 += (double)v * v;
        }
    }
    __shared__ double sh1[256], sh2[256];
    sh1[tid] = s1; sh2[tid] = s2;
    __syncthreads();
    for (int off = blockDim.x >> 1; off > 0; off >>= 1) {
        if (tid < off) { sh1[tid] += sh1[tid + off]; sh2[tid] += sh2[tid + off]; }
        __syncthreads();
    }
    if (tid == 0) {
        unsafeAtomicAdd(&acc[2 * c], sh1[0]);
        unsafeAtomicAdd(&acc[2 * c + 1], sh2[0]);
    }
}

__global__ void k_bn_fin(const double* __restrict__ acc, const float* __restrict__ g,
                         const float* __restrict__ b, double invn,
                         float* __restrict__ scl, float* __restrict__ shf) {
    int c = threadIdx.x;
    if (c < 16) {
        double m = acc[2 * c] * invn;
        double v = acc[2 * c + 1] * invn - m * m;
        double s = (double)g[c] / sqrt(v + 1e-5);
        scl[c] = (float)s;
        shf[c] = (float)((double)b[c] - s * m);
    }
}

__global__ __launch_bounds__(256) void k_bn_res(float* __restrict__ atom,
                                                const float* __restrict__ outb,
                                                const float* __restrict__ scl,
                                                const float* __restrict__ shf) {
    __shared__ float sc[16], sh[16];
    int tid = threadIdx.x;
    if (tid < 16) { sc[tid] = scl[tid]; sh[tid] = shf[tid]; }
    __syncthreads();
    const long total = (long)NN * CC * PP;
    for (long i = (long)blockIdx.x * blockDim.x + tid; i < total;
         i += (long)gridDim.x * blockDim.x) {
        int c = (int)((i / PP) & 15);
        atom[i] += sc[c] * outb[i] + sh[c];
    }
}

// ---------------- mean pooling over graphs (atomic) -------------------------
__global__ __launch_bounds__(256) void k_pool(const float* __restrict__ atom,
                                              const int* __restrict__ gi,
                                              float* __restrict__ crys) {
    int n = blockIdx.x;
    int g = gi[n];
    const float* a = &atom[(size_t)n * CC * PP];
    float* cr = &crys[(size_t)g * CC * PP];
    for (int i = threadIdx.x; i < CC * PP; i += 256) unsafeAtomicAdd(&cr[i], a[i]);
}

// ---------------- conv_to_fc ------------------------------------------------
__global__ __launch_bounds__(256) void k_ctf(const float* __restrict__ crys,
                                             const int* __restrict__ counts,
                                             const float* __restrict__ w,
                                             const float* __restrict__ b,
                                             float* __restrict__ flat) {
    __shared__ float tile[CC * PP];
    __shared__ float ws[CC * CC * 9];
    __shared__ float bs[CC];
    int g = blockIdx.x, tid = threadIdx.x;
    float cnt = (float)counts[g];
    for (int i = tid; i < CC * PP; i += 256) tile[i] = crys[(size_t)g * CC * PP + i] / cnt;
    for (int i = tid; i < CC * CC * 9; i += 256) ws[i] = w[i];
    if (tid < CC) bs[tid] = b[tid];
    __syncthreads();
    for (int i = tid; i < CC * PP; i += 256) {
        int co = i / PP, p = i - co * PP, y = p / WW, x = p - (p / WW) * WW;
        float acc = bs[co];
#pragma unroll
        for (int dy = 0; dy < 3; dy++) {
            int yy = y + dy - 1; if ((unsigned)yy >= (unsigned)HH) continue;
#pragma unroll
            for (int dx = 0; dx < 3; dx++) {
                int xx = x + dx - 1; if ((unsigned)xx >= (unsigned)WW) continue;
                int zoff = yy * WW + xx, tap = dy * 3 + dx;
                const float* tp = &tile[zoff];
                const float* wp = &ws[co * 144 + tap];
#pragma unroll
                for (int ci = 0; ci < CC; ci++) acc += tp[ci * PP] * wp[ci * 9];
            }
        }
        flat[(size_t)g * CC * PP + i] = sp_f(acc);
    }
}

// ---------------- space branch ----------------------------------------------
__global__ __launch_bounds__(256) void k_space1(const int* __restrict__ nsites,
                                                const int* __restrict__ sgs,
                                                const float* __restrict__ w1,
                                                const float* __restrict__ b1,
                                                const float* __restrict__ w2,
                                                const float* __restrict__ b2,
                                                const float* __restrict__ cw,
                                                const float* __restrict__ cb,
                                                float* __restrict__ sembp) {
    __shared__ float outer[256];
    __shared__ float row[16], col[16];
    __shared__ float cws[144], cbs[16];
    int g = blockIdx.x, tid = threadIdx.x;
    if (tid < 16) {
        float ns = (float)nsites[g], sg = (float)sgs[g];
        row[tid] = ns * w1[2 * tid] + sg * w1[2 * tid + 1] + b1[tid];
        col[tid] = ns * w2[2 * tid] + sg * w2[2 * tid + 1] + b2[tid];
        cbs[tid] = cb[tid];
    }
    if (tid >= 64 && tid < 64 + 144) cws[tid - 64] = cw[tid - 64];
    __syncthreads();
    outer[tid] = row[tid >> 4] * col[tid & 15];
    __syncthreads();
    for (int i = tid; i < 16 * 256; i += 256) {
        int c = i >> 8, p = i & 255, y = p >> 4, x = p & 15;
        float acc = cbs[c];
#pragma unroll
        for (int dy = 0; dy < 3; dy++) {
            int yy = y + dy - 1; if ((unsigned)yy >= 16u) continue;
#pragma unroll
            for (int dx = 0; dx < 3; dx++) {
                int xx = x + dx - 1; if ((unsigned)xx >= 16u) continue;
                acc += outer[yy * 16 + xx] * cws[c * 9 + dy * 3 + dx];
            }
        }
        sembp[(size_t)g * 4096 + i] = acc;
    }
}

__global__ __launch_bounds__(256) void k_bn_sp256(const float* __restrict__ X,
                                                  float* __restrict__ Y,
                                                  const float* __restrict__ scl,
                                                  const float* __restrict__ shf) {
    __shared__ float sc[16], sh[16];
    if (threadIdx.x < 16) { sc[threadIdx.x] = scl[threadIdx.x]; sh[threadIdx.x] = shf[threadIdx.x]; }
    __syncthreads();
    int total = BB * 16 * 256;
    for (int i = blockIdx.x * blockDim.x + threadIdx.x; i < total;
         i += gridDim.x * blockDim.x) {
        int c = (i >> 8) & 15;
        Y[i] = sp_f(sc[c] * X[i] + sh[c]);
    }
}

__global__ __launch_bounds__(256) void k_space_conv(const float* __restrict__ X,
                                                    const float* __restrict__ w,
                                                    const float* __restrict__ b,
                                                    float* __restrict__ Y) {
    __shared__ float tile[16 * 256];
    __shared__ float ws[2304], bs[16];
    int g = blockIdx.x, tid = threadIdx.x;
    for (int i = tid; i < 4096; i += 256) tile[i] = X[(size_t)g * 4096 + i];
    for (int i = tid; i < 2304; i += 256) ws[i] = w[i];
    if (tid < 16) bs[tid] = b[tid];
    __syncthreads();
    for (int i = tid; i < 4096; i += 256) {
        int c = i >> 8, p = i & 255, y = p >> 4, x = p & 15;
        float acc = bs[c];
#pragma unroll
        for (int dy = 0; dy < 3; dy++) {
            int yy = y + dy - 1; if ((unsigned)yy >= 16u) continue;
#pragma unroll
            for (int dx = 0; dx < 3; dx++) {
                int xx = x + dx - 1; if ((unsigned)xx >= 16u) continue;
                int tap = dy * 3 + dx;
                const float* wp = &ws[c * 144 + tap];
                const float* tp = &tile[yy * 16 + xx];
#pragma unroll
                for (int ci = 0; ci < 16; ci++) acc += tp[ci * 256] * wp[ci * 9];
            }
        }
        Y[(size_t)g * 4096 + i] = acc;
    }
}

__global__ __launch_bounds__(256) void k_space_tail(const float* __restrict__ ypre,
                                                    const float* __restrict__ scl,
                                                    const float* __restrict__ shf,
                                                    const float* __restrict__ fc3w,
                                                    const float* __restrict__ fc3b,
                                                    float* __restrict__ sout) {
    __shared__ float red[256];
    int g = blockIdx.x, tid = threadIdx.x;
    float val = 0.f;
    if (tid < 144) {
        int c = tid / 9, cell = tid - c * 9, py = cell / 3, px = cell - py * 3;
        float sc = scl[c], sh = shf[c];
        float mx = -INFINITY;
        const float* base = &ypre[((size_t)g * 16 + c) * 256];
        for (int yy = py * 5; yy < py * 5 + 5; yy++)
            for (int xx = px * 5; xx < px * 5 + 5; xx++)
                mx = fmaxf(mx, sc * base[yy * 16 + xx] + sh);
        val = sp_f(mx) * fc3w[tid];
    }
    red[tid] = val;
    __syncthreads();
    for (int off = 128; off > 0; off >>= 1) {
        if (tid < off) red[tid] += red[tid + off];
        __syncthreads();
    }
    if (tid == 0) sout[g] = red[0] + fc3b[0];
}

// ---------------- FC head ---------------------------------------------------
__global__ __launch_bounds__(256) void k_head(const float* __restrict__ flat,
                                              const float* __restrict__ fc1w,
                                              const float* __restrict__ fc1b,
                                              const float* __restrict__ fc2w,
                                              const float* __restrict__ fc2b,
                                              const float* __restrict__ regw,
                                              const float* __restrict__ regb,
                                              const float* __restrict__ sout,
                                              const float* __restrict__ eps,
                                              float* __restrict__ out) {
    int g = blockIdx.x, tid = threadIdx.x;
    __shared__ float h1[32], h2[32];
    int o = tid >> 3, r = tid & 7;
    float part = 0.f;
    const float* fr = &flat[(size_t)g * 2016];
    const float* wr = &fc1w[(size_t)o * 2016];
    for (int j = r; j < 2016; j += 8) part += fr[j] * wr[j];
    part += __shfl_down(part, 4, 8);
    part += __shfl_down(part, 2, 8);
    part += __shfl_down(part, 1, 8);
    if (r == 0) h1[o] = sp_f(part + fc1b[o]);
    __syncthreads();
    if (tid < 32) {
        float a = fc2b[tid];
        for (int j = 0; j < 32; j++) a += h1[j] * fc2w[tid * 32 + j];
        h2[tid] = sp_f(a);
    }
    __syncthreads();
    if (tid == 0) {
        float a = regb[0];
        for (int j = 0; j < 32; j++) a += h2[j] * regw[j];
        out[g] = a + eps[0] * sout[g];
    }
}

// ===========================================================================
extern "C" void kernel_launch(void* const* d_in, const int* in_sizes, int n_in,
                              void* d_out, int out_size, void* d_ws, size_t ws_size,
                              hipStream_t stream) {
    const float* nodes   = (const float*)d_in[0];
    const int*   es      = (const int*)d_in[1];
    const int*   et      = (const int*)d_in[2];
    const int*   gi      = (const int*)d_in[3];
    const int*   cnt     = (const int*)d_in[4];
    const int*   nsites  = (const int*)d_in[5];
    const int*   sgs     = (const int*)d_in[6];
    const float* emb_w   = (const float*)d_in[7];
    const float* emb_b   = (const float*)d_in[8];
    const float* cl_nw   = (const float*)d_in[9];
    const float* cl_ew   = (const float*)d_in[10];
    const float* cl_lw   = (const float*)d_in[11];
    const float* cl_lb   = (const float*)d_in[12];
    const float* cl_bg   = (const float*)d_in[13];
    const float* cl_bb   = (const float*)d_in[14];
    const float* se_w1   = (const float*)d_in[15];
    const float* se_b1   = (const float*)d_in[16];
    const float* se_w2   = (const float*)d_in[17];
    const float* se_b2   = (const float*)d_in[18];
    const float* se_cw   = (const float*)d_in[19];
    const float* se_cb   = (const float*)d_in[20];
    const float* se_bg   = (const float*)d_in[21];
    const float* se_bb   = (const float*)d_in[22];
    const float* sf_cw   = (const float*)d_in[23];
    const float* sf_cb   = (const float*)d_in[24];
    const float* sf_bg   = (const float*)d_in[25];
    const float* sf_bb   = (const float*)d_in[26];
    const float* ctf_w   = (const float*)d_in[27];
    const float* ctf_b   = (const float*)d_in[28];
    const float* fc1_w   = (const float*)d_in[29];
    const float* fc1_b   = (const float*)d_in[30];
    const float* fc2_w   = (const float*)d_in[31];
    const float* fc2_b   = (const float*)d_in[32];
    const float* reg_w   = (const float*)d_in[33];
    const float* reg_b   = (const float*)d_in[34];
    const float* fc3_w   = (const float*)d_in[35];
    const float* fc3_b   = (const float*)d_in[36];
    const float* eps     = (const float*)d_in[37];
    float* out = (float*)d_out;

    const size_t ATOM_B = (size_t)NN * TILE * sizeof(float);   // 33 MB
    const size_t HALO_B = (size_t)NN * ZT * sizeof(float);     // 47.2 MB
    char* ws = (char*)d_ws;
    float*  atom  = (float*)ws;              ws += ATOM_B;
    float*  An    = (float*)ws;              ws += HALO_B;
    float*  Ae    = (float*)ws;              ws += HALO_B;
    float*  outb  = (float*)ws;              ws += ATOM_B;
    double* acc   = (double*)ws;             ws += 256;
    float*  scl   = (float*)ws;              ws += 256;
    float*  shf   = (float*)ws;              ws += 256;
    float*  sout  = (float*)ws;              ws += 256;
    float*  nwT   = (float*)ws;              ws += 4608 * sizeof(float);
    float*  lwT   = (float*)ws;              ws += 4608 * sizeof(float);
    short*  efH   = (short*)ws;              ws += 5120 * sizeof(short);
    short*  efL   = (short*)ws;              ws += 5120 * sizeof(short);
    int*    part  = (int*)ws;                ws += 256;
    int*    flags = (int*)ws;                ws += 256;
    float*  Mdump = (float*)ws;              ws += 4 * TILE * sizeof(float);
    float*  crys  = (float*)ws;              ws += (size_t)BB * TILE * sizeof(float);
    float*  flat  = (float*)ws;              ws += (size_t)BB * TILE * sizeof(float);
    float*  sembp = (float*)ws;              ws += (size_t)BB * 16 * 256 * sizeof(float);
    float*  semb  = (float*)ws;              ws += (size_t)BB * 16 * 256 * sizeof(float);
    float*  ypre  = (float*)ws;              ws += (size_t)BB * 16 * 256 * sizeof(float);

    // ---- embedding
    k_embed<<<NN, 256, 0, stream>>>(nodes, emb_w, emb_b, atom);

    // ---- 3 conv layers (fp32 production path)
    for (int l = 0; l < 3; l++) {
        const float* nw = cl_nw + (size_t)l * CC * CC * 9;
        const float* ew = cl_ew + (size_t)l * CC * CC * 9;
        const float* lw = cl_lw + (size_t)l * 32 * CC * 9;
        const float* lb = cl_lb + (size_t)l * 32;
        const float* bg = cl_bg + (size_t)l * 16;
        const float* bb = cl_bb + (size_t)l * 16;

        k_wT2<<<9, 256, 0, stream>>>(nw, ew, nwT);
        k_wT<<<18, 256, 0, stream>>>(lw, lwT);
        k_node_conv2<<<NN / 2, 256, 0, stream>>>(atom, nwT, An, Ae);

        if (l == 0) {
            // MFMA self-calibration suite; spins fire only on FAILURE
            hipMemsetAsync(flags, 0, 16, stream);
            k_probe1<<<1, 64, 0, stream>>>(flags);
            k_pairprobe<<<1, 64, 0, stream>>>(part, flags);
            k_wprep_cal<<<20, 256, 0, stream>>>(lw, part, efH, efL);
            k_mfma4_cal<<<4, 256, 0, stream>>>(An, Ae, es, et, efH, efL, lb, Mdump);
            k_scmp<<<4, 256, 0, stream>>>(An, Ae, es, et, lw, lb, Mdump, flags);
            k_s1<<<1, 64, 0, stream>>>(flags);
            k_s2<<<1, 64, 0, stream>>>(flags);
            k_s3<<<1, 64, 0, stream>>>(flags);
        }

        hipMemcpyAsync(outb, atom, ATOM_B, hipMemcpyDeviceToDevice, stream);
        k_edge<<<EE / 2, 256, 0, stream>>>(An, Ae, es, et, lwT, lb, outb);
        hipMemsetAsync(acc, 0, 16 * 2 * sizeof(double), stream);
        k_bn_stats<16, 126><<<dim3(64, 16), 128, 0, stream>>>(outb, acc, NN);
        k_bn_fin<<<1, 16, 0, stream>>>(acc, bg, bb, 1.0 / ((double)NN * PP), scl, shf);
        k_bn_res<<<2048, 256, 0, stream>>>(atom, outb, scl, shf);
    }

    // ---- space branch
    k_space1<<<BB, 256, 0, stream>>>(nsites, sgs, se_w1, se_b1, se_w2, se_b2,
                                     se_cw, se_cb, sembp);
    hipMemsetAsync(acc, 0, 16 * 2 * sizeof(double), stream);
    k_bn_stats<16, 256><<<dim3(8, 16), 256, 0, stream>>>(sembp, acc, BB);
    k_bn_fin<<<1, 16, 0, stream>>>(acc, se_bg, se_bb, 1.0 / (BB * 256.0), scl, shf);
    k_bn_sp256<<<256, 256, 0, stream>>>(sembp, semb, scl, shf);
    k_space_conv<<<BB, 256, 0, stream>>>(semb, sf_cw, sf_cb, ypre);
    hipMemsetAsync(acc, 0, 16 * 2 * sizeof(double), stream);
    k_bn_stats<16, 256><<<dim3(8, 16), 256, 0, stream>>>(ypre, acc, BB);
    k_bn_fin<<<1, 16, 0, stream>>>(acc, sf_bg, sf_bb, 1.0 / (BB * 256.0), scl, shf);
    k_space_tail<<<BB, 256, 0, stream>>>(ypre, scl, shf, fc3_w, fc3_b, sout);

    // ---- pooling + conv_to_fc + head
    hipMemsetAsync(crys, 0, (size_t)BB * TILE * sizeof(float), stream);
    k_pool<<<NN, 256, 0, stream>>>(atom, gi, crys);
    k_ctf<<<BB, 256, 0, stream>>>(crys, cnt, ctf_w, ctf_b, flat);
    k_head<<<BB, 256, 0, stream>>>(flat, fc1_w, fc1_b, fc2_w, fc2_b,
                                   reg_w, reg_b, sout, eps, out);
}

// Round 8
// 1810.313 us; speedup vs baseline: 9.8175x; 3.2002x over previous
//
#include <hip/hip_runtime.h>
#include <math.h>

#define HH 7
#define WW 18
#define PP 126        // HH*WW
#define CC 16
#define NN 4096
#define EE 16384
#define BB 64
#define TILE 2016               // CC*PP, std layout
#define ZT 2880                 // 16*9*20 haloed tile (An/Ae layout)

__device__ __forceinline__ float sp_f(float x) {
    // softplus, JAX-stable form: max(x,0)+log1p(exp(-|x|))
    return fmaxf(x, 0.f) + log1pf(expf(-fabsf(x)));
}

// ---------------- fp32 weight transposes -> [tap][ci][co16][2] --------------
__global__ void k_wT(const float* __restrict__ w, float* __restrict__ wT) {
    int i = blockIdx.x * 256 + threadIdx.x;
    if (i < 32 * 144) {
        int co = i / 144, r = i - co * 144, ci = r / 9, tap = r - ci * 9;
        int half = co >> 4, coo = co & 15;
        wT[((tap * 16 + ci) * 16 + coo) * 2 + half] = w[i];
    }
}
__global__ void k_wT2(const float* __restrict__ wN, const float* __restrict__ wE,
                      float* __restrict__ wT) {
    int i = blockIdx.x * 256 + threadIdx.x;
    if (i < 16 * 144) {
        int co = i / 144, r = i - co * 144, ci = r / 9, tap = r - ci * 9;
        wT[((tap * 16 + ci) * 16 + co) * 2 + 0] = wN[i];
        wT[((tap * 16 + ci) * 16 + co) * 2 + 1] = wE[i];
    }
}

// ---------------- embedding -------------------------------------------------
__global__ __launch_bounds__(256) void k_embed(const float* __restrict__ nodes,
                                               const float* __restrict__ w,
                                               const float* __restrict__ b,
                                               float* __restrict__ atom) {
    __shared__ float tile[PP];
    __shared__ float ws[CC * 9];
    __shared__ float bs[CC];
    int n = blockIdx.x, tid = threadIdx.x;
    for (int i = tid; i < PP; i += 256) tile[i] = nodes[n * PP + i];
    for (int i = tid; i < CC * 9; i += 256) ws[i] = w[i];
    if (tid < CC) bs[tid] = b[tid];
    __syncthreads();
    for (int i = tid; i < CC * PP; i += 256) {
        int c = i / PP, p = i - c * PP, y = p / WW, x = p - (p / WW) * WW;
        float acc = bs[c];
#pragma unroll
        for (int dy = 0; dy < 3; dy++) {
            int yy = y + dy - 1; if ((unsigned)yy >= (unsigned)HH) continue;
#pragma unroll
            for (int dx = 0; dx < 3; dx++) {
                int xx = x + dx - 1; if ((unsigned)xx >= (unsigned)WW) continue;
                acc += tile[yy * WW + xx] * ws[c * 9 + dy * 3 + dx];
            }
        }
        atom[(size_t)n * CC * PP + i] = sp_f(acc);
    }
}

// ---------------- branch-free fp32 conv core --------------------------------
// zt: haloed tile [16 ci][9 rows][20 cols], halos zero. ws: [9][16][16][2].
__device__ __forceinline__ void conv_body(const float* zt,
                                          const float (*ws)[16][16][2],
                                          int co, int y, float* hA, float* hB) {
    for (int ci = 0; ci < 16; ci++) {
        const float* zb = zt + ci * 180 + y * 20;
#pragma unroll
        for (int dy = 0; dy < 3; dy++) {
            const float* zr = zb + dy * 20;
            float4 q0 = *(const float4*)&zr[0];
            float4 q1 = *(const float4*)&zr[4];
            float4 q2 = *(const float4*)&zr[8];
            float4 q3 = *(const float4*)&zr[12];
            float4 q4 = *(const float4*)&zr[16];
            float r[20];
            r[0]=q0.x; r[1]=q0.y; r[2]=q0.z; r[3]=q0.w;
            r[4]=q1.x; r[5]=q1.y; r[6]=q1.z; r[7]=q1.w;
            r[8]=q2.x; r[9]=q2.y; r[10]=q2.z; r[11]=q2.w;
            r[12]=q3.x; r[13]=q3.y; r[14]=q3.z; r[15]=q3.w;
            r[16]=q4.x; r[17]=q4.y; r[18]=q4.z; r[19]=q4.w;
            float2 w0 = *(const float2*)&ws[dy * 3 + 0][ci][co][0];
            float2 w1 = *(const float2*)&ws[dy * 3 + 1][ci][co][0];
            float2 w2 = *(const float2*)&ws[dy * 3 + 2][ci][co][0];
#pragma unroll
            for (int x = 0; x < 18; x++) {
                hA[x] = fmaf(r[x],     w0.x, hA[x]);
                hA[x] = fmaf(r[x + 1], w1.x, hA[x]);
                hA[x] = fmaf(r[x + 2], w2.x, hA[x]);
                hB[x] = fmaf(r[x],     w0.y, hB[x]);
                hB[x] = fmaf(r[x + 1], w1.y, hB[x]);
                hB[x] = fmaf(r[x + 2], w2.y, hB[x]);
            }
        }
    }
}

// ------------- per-node dual conv, 2 nodes/block; An/Ae OUT in halo layout --
__global__ __launch_bounds__(256) void k_node_conv2(const float* __restrict__ atom,
                                                    const float* __restrict__ wT,
                                                    float* __restrict__ An,
                                                    float* __restrict__ Ae) {
    __shared__ __align__(16) float zf[2 * ZT];
    __shared__ __align__(16) float ws[9][16][16][2];
    int tid = threadIdx.x;
    int n0 = blockIdx.x * 2;
    for (int i = tid; i < 2 * ZT; i += 256) {
        int e2 = i / ZT, r = i - e2 * ZT;
        int ci = r / 180, rr = r - ci * 180;
        int yy = rr / 20, xx = rr - yy * 20;
        float v = 0.f;
        if ((unsigned)(yy - 1) < 7u && (unsigned)(xx - 1) < 18u)
            v = atom[(size_t)(n0 + e2) * TILE + ci * 126 + (yy - 1) * 18 + (xx - 1)];
        zf[i] = v;
    }
    for (int i = tid; i < 4608; i += 256) ((float*)ws)[i] = wT[i];
    __syncthreads();
    int grp = tid >> 7, lt = tid & 127;
    bool act = lt < 112;
    int co = lt & 15, y = lt >> 4;
    float hA[18], hB[18];
#pragma unroll
    for (int x = 0; x < 18; x++) { hA[x] = 0.f; hB[x] = 0.f; }
    if (act) conv_body(&zf[grp * ZT], ws, co, y, hA, hB);
    __syncthreads();
    // zero entire buffer once (halo zeros for output), then stage hA (node out)
    for (int i = tid; i < 2 * ZT; i += 256) zf[i] = 0.f;
    __syncthreads();
    int base = grp * ZT + co * 180 + (y + 1) * 20 + 1;
    if (act) {
#pragma unroll
        for (int x = 0; x < 18; x++) zf[base + x] = hA[x];
    }
    __syncthreads();
    for (int i = tid; i < 2 * (ZT / 4); i += 256) {
        int e2 = i / (ZT / 4), j = i - e2 * (ZT / 4);
        ((float4*)&An[(size_t)(n0 + e2) * ZT])[j] = ((const float4*)zf)[i];
    }
    __syncthreads();
    // interior fully rewritten by same threads; halos still zero
    if (act) {
#pragma unroll
        for (int x = 0; x < 18; x++) zf[base + x] = hB[x];
    }
    __syncthreads();
    for (int i = tid; i < 2 * (ZT / 4); i += 256) {
        int e2 = i / (ZT / 4), j = i - e2 * (ZT / 4);
        ((float4*)&Ae[(size_t)(n0 + e2) * ZT])[j] = ((const float4*)zf)[i];
    }
}

// ---------------- per-edge conv, 2 edges/block; An/Ae IN halo layout --------
__global__ __launch_bounds__(256) void k_edge(const float* __restrict__ An,
                                              const float* __restrict__ Ae,
                                              const int* __restrict__ es,
                                              const int* __restrict__ et,
                                              const float* __restrict__ wT,
                                              const float* __restrict__ lb,
                                              float* __restrict__ outb) {
    __shared__ __align__(16) float zf[2 * ZT];
    __shared__ __align__(16) float ws[9][16][16][2];
    int tid = threadIdx.x;
    int e0 = blockIdx.x * 2;
    int s0 = es[e0], t0 = et[e0], s1 = es[e0 + 1], t1 = et[e0 + 1];
    // pure float4 load: halos 0*0 -> elu(0)=0 preserved
    for (int i = tid; i < 2 * (ZT / 4); i += 256) {
        int e2 = i / (ZT / 4), j = i - e2 * (ZT / 4);
        float4 a4 = ((const float4*)&An[(size_t)(e2 ? s1 : s0) * ZT])[j];
        float4 b4 = ((const float4*)&Ae[(size_t)(e2 ? t1 : t0) * ZT])[j];
        float4 res;
        res.x = a4.x * b4.x; res.x = res.x > 0.f ? res.x : expm1f(res.x);
        res.y = a4.y * b4.y; res.y = res.y > 0.f ? res.y : expm1f(res.y);
        res.z = a4.z * b4.z; res.z = res.z > 0.f ? res.z : expm1f(res.z);
        res.w = a4.w * b4.w; res.w = res.w > 0.f ? res.w : expm1f(res.w);
        ((float4*)zf)[i] = res;
    }
    for (int i = tid; i < 4608; i += 256) ((float*)ws)[i] = wT[i];
    __syncthreads();
    int grp = tid >> 7, lt = tid & 127;
    bool act = lt < 112;
    int co = lt & 15, y = lt >> 4;
    float hA[18], hB[18];
#pragma unroll
    for (int x = 0; x < 18; x++) { hA[x] = 0.f; hB[x] = 0.f; }
    if (act) conv_body(&zf[grp * ZT], ws, co, y, hA, hB);
    __syncthreads();
    // stage msg in std layout (zf dead), then coalesced atomic scatter
    float* msgL = zf;
    if (act) {
        float bf = lb[co], bc = lb[co + 16];
        int base = grp * TILE + co * 126 + y * 18;
#pragma unroll
        for (int x = 0; x < 18; x++) {
            float hfv = hA[x] + bf, hcv = hB[x] + bc;
            msgL[base + x] = (1.f / (1.f + expf(-hfv))) * sp_f(hcv);
        }
    }
    __syncthreads();
    for (int i = tid; i < 2 * TILE; i += 256) {
        int e2 = i / TILE, j = i - e2 * TILE;
        unsafeAtomicAdd(&outb[(size_t)(e2 ? s1 : s0) * TILE + j], msgL[i]);
    }
}

// ---------------- BN statistics (double accumulation) -----------------------
template <int C, int S>
__global__ void k_bn_stats(const float* __restrict__ X, double* __restrict__ acc, int M) {
    int c = blockIdx.y, tid = threadIdx.x;
    double s1 = 0.0, s2 = 0.0;
    for (int m = blockIdx.x; m < M; m += gridDim.x) {
        const float* xr = &X[((size_t)m * C + c) * S];
        for (int s = tid; s < S; s += blockDim.x) {
            float v = xr[s];
            s1 += v; s2 += (double)v * v;
        }
    }
    __shared__ double sh1[256], sh2[256];
    sh1[tid] = s1; sh2[tid] = s2;
    __syncthreads();
    for (int off = blockDim.x >> 1; off > 0; off >>= 1) {
        if (tid < off) { sh1[tid] += sh1[tid + off]; sh2[tid] += sh2[tid + off]; }
        __syncthreads();
    }
    if (tid == 0) {
        unsafeAtomicAdd(&acc[2 * c], sh1[0]);
        unsafeAtomicAdd(&acc[2 * c + 1], sh2[0]);
    }
}

__global__ void k_bn_fin(const double* __restrict__ acc, const float* __restrict__ g,
                         const float* __restrict__ b, double invn,
                         float* __restrict__ scl, float* __restrict__ shf) {
    int c = threadIdx.x;
    if (c < 16) {
        double m = acc[2 * c] * invn;
        double v = acc[2 * c + 1] * invn - m * m;
        double s = (double)g[c] / sqrt(v + 1e-5);
        scl[c] = (float)s;
        shf[c] = (float)((double)b[c] - s * m);
    }
}

__global__ __launch_bounds__(256) void k_bn_res(float* __restrict__ atom,
                                                const float* __restrict__ outb,
                                                const float* __restrict__ scl,
                                                const float* __restrict__ shf) {
    __shared__ float sc[16], sh[16];
    int tid = threadIdx.x;
    if (tid < 16) { sc[tid] = scl[tid]; sh[tid] = shf[tid]; }
    __syncthreads();
    const long total = (long)NN * CC * PP;
    for (long i = (long)blockIdx.x * blockDim.x + tid; i < total;
         i += (long)gridDim.x * blockDim.x) {
        int c = (int)((i / PP) & 15);
        atom[i] += sc[c] * outb[i] + sh[c];
    }
}

// ---------------- mean pooling over graphs (atomic) -------------------------
__global__ __launch_bounds__(256) void k_pool(const float* __restrict__ atom,
                                              const int* __restrict__ gi,
                                              float* __restrict__ crys) {
    int n = blockIdx.x;
    int g = gi[n];
    const float* a = &atom[(size_t)n * CC * PP];
    float* cr = &crys[(size_t)g * CC * PP];
    for (int i = threadIdx.x; i < CC * PP; i += 256) unsafeAtomicAdd(&cr[i], a[i]);
}

// ---------------- conv_to_fc ------------------------------------------------
__global__ __launch_bounds__(256) void k_ctf(const float* __restrict__ crys,
                                             const int* __restrict__ counts,
                                             const float* __restrict__ w,
                                             const float* __restrict__ b,
                                             float* __restrict__ flat) {
    __shared__ float tile[CC * PP];
    __shared__ float ws[CC * CC * 9];
    __shared__ float bs[CC];
    int g = blockIdx.x, tid = threadIdx.x;
    float cnt = (float)counts[g];
    for (int i = tid; i < CC * PP; i += 256) tile[i] = crys[(size_t)g * CC * PP + i] / cnt;
    for (int i = tid; i < CC * CC * 9; i += 256) ws[i] = w[i];
    if (tid < CC) bs[tid] = b[tid];
    __syncthreads();
    for (int i = tid; i < CC * PP; i += 256) {
        int co = i / PP, p = i - co * PP, y = p / WW, x = p - (p / WW) * WW;
        float acc = bs[co];
#pragma unroll
        for (int dy = 0; dy < 3; dy++) {
            int yy = y + dy - 1; if ((unsigned)yy >= (unsigned)HH) continue;
#pragma unroll
            for (int dx = 0; dx < 3; dx++) {
                int xx = x + dx - 1; if ((unsigned)xx >= (unsigned)WW) continue;
                int zoff = yy * WW + xx, tap = dy * 3 + dx;
                const float* tp = &tile[zoff];
                const float* wp = &ws[co * 144 + tap];
#pragma unroll
                for (int ci = 0; ci < CC; ci++) acc += tp[ci * PP] * wp[ci * 9];
            }
        }
        flat[(size_t)g * CC * PP + i] = sp_f(acc);
    }
}

// ---------------- space branch ----------------------------------------------
__global__ __launch_bounds__(256) void k_space1(const int* __restrict__ nsites,
                                                const int* __restrict__ sgs,
                                                const float* __restrict__ w1,
                                                const float* __restrict__ b1,
                                                const float* __restrict__ w2,
                                                const float* __restrict__ b2,
                                                const float* __restrict__ cw,
                                                const float* __restrict__ cb,
                                                float* __restrict__ sembp) {
    __shared__ float outer[256];
    __shared__ float row[16], col[16];
    __shared__ float cws[144], cbs[16];
    int g = blockIdx.x, tid = threadIdx.x;
    if (tid < 16) {
        float ns = (float)nsites[g], sg = (float)sgs[g];
        row[tid] = ns * w1[2 * tid] + sg * w1[2 * tid + 1] + b1[tid];
        col[tid] = ns * w2[2 * tid] + sg * w2[2 * tid + 1] + b2[tid];
        cbs[tid] = cb[tid];
    }
    if (tid >= 64 && tid < 64 + 144) cws[tid - 64] = cw[tid - 64];
    __syncthreads();
    outer[tid] = row[tid >> 4] * col[tid & 15];
    __syncthreads();
    for (int i = tid; i < 16 * 256; i += 256) {
        int c = i >> 8, p = i & 255, y = p >> 4, x = p & 15;
        float acc = cbs[c];
#pragma unroll
        for (int dy = 0; dy < 3; dy++) {
            int yy = y + dy - 1; if ((unsigned)yy >= 16u) continue;
#pragma unroll
            for (int dx = 0; dx < 3; dx++) {
                int xx = x + dx - 1; if ((unsigned)xx >= 16u) continue;
                acc += outer[yy * 16 + xx] * cws[c * 9 + dy * 3 + dx];
            }
        }
        sembp[(size_t)g * 4096 + i] = acc;
    }
}

__global__ __launch_bounds__(256) void k_bn_sp256(const float* __restrict__ X,
                                                  float* __restrict__ Y,
                                                  const float* __restrict__ scl,
                                                  const float* __restrict__ shf) {
    __shared__ float sc[16], sh[16];
    if (threadIdx.x < 16) { sc[threadIdx.x] = scl[threadIdx.x]; sh[threadIdx.x] = shf[threadIdx.x]; }
    __syncthreads();
    int total = BB * 16 * 256;
    for (int i = blockIdx.x * blockDim.x + threadIdx.x; i < total;
         i += gridDim.x * blockDim.x) {
        int c = (i >> 8) & 15;
        Y[i] = sp_f(sc[c] * X[i] + sh[c]);
    }
}

__global__ __launch_bounds__(256) void k_space_conv(const float* __restrict__ X,
                                                    const float* __restrict__ w,
                                                    const float* __restrict__ b,
                                                    float* __restrict__ Y) {
    __shared__ float tile[16 * 256];
    __shared__ float ws[2304], bs[16];
    int g = blockIdx.x, tid = threadIdx.x;
    for (int i = tid; i < 4096; i += 256) tile[i] = X[(size_t)g * 4096 + i];
    for (int i = tid; i < 2304; i += 256) ws[i] = w[i];
    if (tid < 16) bs[tid] = b[tid];
    __syncthreads();
    for (int i = tid; i < 4096; i += 256) {
        int c = i >> 8, p = i & 255, y = p >> 4, x = p & 15;
        float acc = bs[c];
#pragma unroll
        for (int dy = 0; dy < 3; dy++) {
            int yy = y + dy - 1; if ((unsigned)yy >= 16u) continue;
#pragma unroll
            for (int dx = 0; dx < 3; dx++) {
                int xx = x + dx - 1; if ((unsigned)xx >= 16u) continue;
                int tap = dy * 3 + dx;
                const float* wp = &ws[c * 144 + tap];
                const float* tp = &tile[yy * 16 + xx];
#pragma unroll
                for (int ci = 0; ci < 16; ci++) acc += tp[ci * 256] * wp[ci * 9];
            }
        }
        Y[(size_t)g * 4096 + i] = acc;
    }
}

__global__ __launch_bounds__(256) void k_space_tail(const float* __restrict__ ypre,
                                                    const float* __restrict__ scl,
                                                    const float* __restrict__ shf,
                                                    const float* __restrict__ fc3w,
                                                    const float* __restrict__ fc3b,
                                                    float* __restrict__ sout) {
    __shared__ float red[256];
    int g = blockIdx.x, tid = threadIdx.x;
    float val = 0.f;
    if (tid < 144) {
        int c = tid / 9, cell = tid - c * 9, py = cell / 3, px = cell - py * 3;
        float sc = scl[c], sh = shf[c];
        float mx = -INFINITY;
        const float* base = &ypre[((size_t)g * 16 + c) * 256];
        for (int yy = py * 5; yy < py * 5 + 5; yy++)
            for (int xx = px * 5; xx < px * 5 + 5; xx++)
                mx = fmaxf(mx, sc * base[yy * 16 + xx] + sh);
        val = sp_f(mx) * fc3w[tid];
    }
    red[tid] = val;
    __syncthreads();
    for (int off = 128; off > 0; off >>= 1) {
        if (tid < off) red[tid] += red[tid + off];
        __syncthreads();
    }
    if (tid == 0) sout[g] = red[0] + fc3b[0];
}

// ---------------- FC head ---------------------------------------------------
__global__ __launch_bounds__(256) void k_head(const float* __restrict__ flat,
                                              const float* __restrict__ fc1w,
                                              const float* __restrict__ fc1b,
                                              const float* __restrict__ fc2w,
                                              const float* __restrict__ fc2b,
                                              const float* __restrict__ regw,
                                              const float* __restrict__ regb,
                                              const float* __restrict__ sout,
                                              const float* __restrict__ eps,
                                              float* __restrict__ out) {
    int g = blockIdx.x, tid = threadIdx.x;
    __shared__ float h1[32], h2[32];
    int o = tid >> 3, r = tid & 7;
    float part = 0.f;
    const float* fr = &flat[(size_t)g * 2016];
    const float* wr = &fc1w[(size_t)o * 2016];
    for (int j = r; j < 2016; j += 8) part += fr[j] * wr[j];
    part += __shfl_down(part, 4, 8);
    part += __shfl_down(part, 2, 8);
    part += __shfl_down(part, 1, 8);
    if (r == 0) h1[o] = sp_f(part + fc1b[o]);
    __syncthreads();
    if (tid < 32) {
        float a = fc2b[tid];
        for (int j = 0; j < 32; j++) a += h1[j] * fc2w[tid * 32 + j];
        h2[tid] = sp_f(a);
    }
    __syncthreads();
    if (tid == 0) {
        float a = regb[0];
        for (int j = 0; j < 32; j++) a += h2[j] * regw[j];
        out[g] = a + eps[0] * sout[g];
    }
}

// ===========================================================================
extern "C" void kernel_launch(void* const* d_in, const int* in_sizes, int n_in,
                              void* d_out, int out_size, void* d_ws, size_t ws_size,
                              hipStream_t stream) {
    const float* nodes   = (const float*)d_in[0];
    const int*   es      = (const int*)d_in[1];
    const int*   et      = (const int*)d_in[2];
    const int*   gi      = (const int*)d_in[3];
    const int*   cnt     = (const int*)d_in[4];
    const int*   nsites  = (const int*)d_in[5];
    const int*   sgs     = (const int*)d_in[6];
    const float* emb_w   = (const float*)d_in[7];
    const float* emb_b   = (const float*)d_in[8];
    const float* cl_nw   = (const float*)d_in[9];
    const float* cl_ew   = (const float*)d_in[10];
    const float* cl_lw   = (const float*)d_in[11];
    const float* cl_lb   = (const float*)d_in[12];
    const float* cl_bg   = (const float*)d_in[13];
    const float* cl_bb   = (const float*)d_in[14];
    const float* se_w1   = (const float*)d_in[15];
    const float* se_b1   = (const float*)d_in[16];
    const float* se_w2   = (const float*)d_in[17];
    const float* se_b2   = (const float*)d_in[18];
    const float* se_cw   = (const float*)d_in[19];
    const float* se_cb   = (const float*)d_in[20];
    const float* se_bg   = (const float*)d_in[21];
    const float* se_bb   = (const float*)d_in[22];
    const float* sf_cw   = (const float*)d_in[23];
    const float* sf_cb   = (const float*)d_in[24];
    const float* sf_bg   = (const float*)d_in[25];
    const float* sf_bb   = (const float*)d_in[26];
    const float* ctf_w   = (const float*)d_in[27];
    const float* ctf_b   = (const float*)d_in[28];
    const float* fc1_w   = (const float*)d_in[29];
    const float* fc1_b   = (const float*)d_in[30];
    const float* fc2_w   = (const float*)d_in[31];
    const float* fc2_b   = (const float*)d_in[32];
    const float* reg_w   = (const float*)d_in[33];
    const float* reg_b   = (const float*)d_in[34];
    const float* fc3_w   = (const float*)d_in[35];
    const float* fc3_b   = (const float*)d_in[36];
    const float* eps     = (const float*)d_in[37];
    float* out = (float*)d_out;

    const size_t ATOM_B = (size_t)NN * TILE * sizeof(float);   // 33 MB
    const size_t HALO_B = (size_t)NN * ZT * sizeof(float);     // 47.2 MB
    char* ws = (char*)d_ws;
    float*  atom  = (float*)ws;              ws += ATOM_B;
    float*  An    = (float*)ws;              ws += HALO_B;
    float*  Ae    = (float*)ws;              ws += HALO_B;
    float*  outb  = (float*)ws;              ws += ATOM_B;
    double* acc   = (double*)ws;             ws += 256;
    float*  scl   = (float*)ws;              ws += 256;
    float*  shf   = (float*)ws;              ws += 256;
    float*  sout  = (float*)ws;              ws += 256;
    float*  nwT   = (float*)ws;              ws += 4608 * sizeof(float);
    float*  lwT   = (float*)ws;              ws += 4608 * sizeof(float);
    float*  crys  = (float*)ws;              ws += (size_t)BB * TILE * sizeof(float);
    float*  flat  = (float*)ws;              ws += (size_t)BB * TILE * sizeof(float);
    float*  sembp = (float*)ws;              ws += (size_t)BB * 16 * 256 * sizeof(float);
    float*  semb  = (float*)ws;              ws += (size_t)BB * 16 * 256 * sizeof(float);
    float*  ypre  = (float*)ws;              ws += (size_t)BB * 16 * 256 * sizeof(float);

    // ---- embedding
    k_embed<<<NN, 256, 0, stream>>>(nodes, emb_w, emb_b, atom);

    // ---- 3 conv layers (fp32 production path)
    for (int l = 0; l < 3; l++) {
        const float* nw = cl_nw + (size_t)l * CC * CC * 9;
        const float* ew = cl_ew + (size_t)l * CC * CC * 9;
        const float* lw = cl_lw + (size_t)l * 32 * CC * 9;
        const float* lb = cl_lb + (size_t)l * 32;
        const float* bg = cl_bg + (size_t)l * 16;
        const float* bb = cl_bb + (size_t)l * 16;

        k_wT2<<<9, 256, 0, stream>>>(nw, ew, nwT);
        k_wT<<<18, 256, 0, stream>>>(lw, lwT);
        k_node_conv2<<<NN / 2, 256, 0, stream>>>(atom, nwT, An, Ae);
        hipMemcpyAsync(outb, atom, ATOM_B, hipMemcpyDeviceToDevice, stream);
        k_edge<<<EE / 2, 256, 0, stream>>>(An, Ae, es, et, lwT, lb, outb);
        hipMemsetAsync(acc, 0, 16 * 2 * sizeof(double), stream);
        k_bn_stats<16, 126><<<dim3(64, 16), 128, 0, stream>>>(outb, acc, NN);
        k_bn_fin<<<1, 16, 0, stream>>>(acc, bg, bb, 1.0 / ((double)NN * PP), scl, shf);
        k_bn_res<<<2048, 256, 0, stream>>>(atom, outb, scl, shf);
    }

    // ---- space branch
    k_space1<<<BB, 256, 0, stream>>>(nsites, sgs, se_w1, se_b1, se_w2, se_b2,
                                     se_cw, se_cb, sembp);
    hipMemsetAsync(acc, 0, 16 * 2 * sizeof(double), stream);
    k_bn_stats<16, 256><<<dim3(8, 16), 256, 0, stream>>>(sembp, acc, BB);
    k_bn_fin<<<1, 16, 0, stream>>>(acc, se_bg, se_bb, 1.0 / (BB * 256.0), scl, shf);
    k_bn_sp256<<<256, 256, 0, stream>>>(sembp, semb, scl, shf);
    k_space_conv<<<BB, 256, 0, stream>>>(semb, sf_cw, sf_cb, ypre);
    hipMemsetAsync(acc, 0, 16 * 2 * sizeof(double), stream);
    k_bn_stats<16, 256><<<dim3(8, 16), 256, 0, stream>>>(ypre, acc, BB);
    k_bn_fin<<<1, 16, 0, stream>>>(acc, sf_bg, sf_bb, 1.0 / (BB * 256.0), scl, shf);
    k_space_tail<<<BB, 256, 0, stream>>>(ypre, scl, shf, fc3_w, fc3_b, sout);

    // ---- pooling + conv_to_fc + head
    hipMemsetAsync(crys, 0, (size_t)BB * TILE * sizeof(float), stream);
    k_pool<<<NN, 256, 0, stream>>>(atom, gi, crys);
    k_ctf<<<BB, 256, 0, stream>>>(crys, cnt, ctf_w, ctf_b, flat);
    k_head<<<BB, 256, 0, stream>>>(flat, fc1_w, fc1_b, fc2_w, fc2_b,
                                   reg_w, reg_b, sout, eps, out);
}